// Round 1
// baseline (566.965 us; speedup 1.0000x reference)
//
#include <hip/hip_runtime.h>
#include <cstddef>

namespace {

constexpr int Bn   = 4;
constexpr int Ln   = 1024;
constexpr int INn  = 256;
constexpr int DMn  = 1024;
constexpr int DSn  = 16;
constexpr int DCn  = 4;
constexpr int DIn  = 2048;
constexpr int DTRn = 64;
constexpr int XPW  = DTRn + DSn;   // 80: dt (64) + B (16) rows of x_proj
constexpr int NCHUNK = 16;
constexpr int CHUNK  = Ln / NCHUNK; // 64

constexpr int TILE = 64;
constexpr int BKk  = 16;
constexpr int LDSS = TILE + 4; // 68: keeps float4 LDS reads 16B-aligned, 2-way conflicts only

__device__ __forceinline__ float silu_(float x) { return x / (1.f + __expf(-x)); }

// C[m][n] = act( sum_k A[m][k]*Bw[n][k] + bias[n] ), A row-major lda, Bw row-major ldb.
// M is grid-implied (grid.y*TILE), must be multiple of TILE. N may be ragged.
template<int ACT, bool HAS_BIAS>
__global__ __launch_bounds__(256)
void gemm_nt(const float* __restrict__ A, int lda,
             const float* __restrict__ Bw, int ldb,
             const float* __restrict__ bias,
             float* __restrict__ C, int ldc,
             int N, int K) {
    __shared__ float As[BKk][LDSS];
    __shared__ float Bs[BKk][LDSS];
    const int tid = threadIdx.x;
    const int tx = tid & 15, ty = tid >> 4;
    const int m0 = blockIdx.y * TILE, n0 = blockIdx.x * TILE;
    const int lr = tid >> 2;        // 0..63
    const int lc = (tid & 3) * 4;   // 0,4,8,12
    const float* Aload = A + (size_t)(m0 + lr) * lda + lc;
    const bool bvalid = (n0 + lr) < N;
    const float* Bload = Bw + (size_t)(bvalid ? (n0 + lr) : 0) * ldb + lc;
    float acc[4][4] = {};
    for (int k0 = 0; k0 < K; k0 += BKk) {
        float4 av = *(const float4*)(Aload + k0);
        float4 bv = bvalid ? *(const float4*)(Bload + k0) : float4{0.f, 0.f, 0.f, 0.f};
        As[lc + 0][lr] = av.x; As[lc + 1][lr] = av.y; As[lc + 2][lr] = av.z; As[lc + 3][lr] = av.w;
        Bs[lc + 0][lr] = bv.x; Bs[lc + 1][lr] = bv.y; Bs[lc + 2][lr] = bv.z; Bs[lc + 3][lr] = bv.w;
        __syncthreads();
        #pragma unroll
        for (int kk = 0; kk < BKk; ++kk) {
            const float a0 = As[kk][ty * 4 + 0], a1 = As[kk][ty * 4 + 1];
            const float a2 = As[kk][ty * 4 + 2], a3 = As[kk][ty * 4 + 3];
            const float b0 = Bs[kk][tx * 4 + 0], b1 = Bs[kk][tx * 4 + 1];
            const float b2 = Bs[kk][tx * 4 + 2], b3 = Bs[kk][tx * 4 + 3];
            acc[0][0] += a0 * b0; acc[0][1] += a0 * b1; acc[0][2] += a0 * b2; acc[0][3] += a0 * b3;
            acc[1][0] += a1 * b0; acc[1][1] += a1 * b1; acc[1][2] += a1 * b2; acc[1][3] += a1 * b3;
            acc[2][0] += a2 * b0; acc[2][1] += a2 * b1; acc[2][2] += a2 * b2; acc[2][3] += a2 * b3;
            acc[3][0] += a3 * b0; acc[3][1] += a3 * b1; acc[3][2] += a3 * b2; acc[3][3] += a3 * b3;
        }
        __syncthreads();
    }
    #pragma unroll
    for (int i = 0; i < 4; ++i) {
        const int m = m0 + ty * 4 + i;
        #pragma unroll
        for (int j = 0; j < 4; ++j) {
            const int n = n0 + tx * 4 + j;
            if (n < N) {
                float v = acc[i][j];
                if (HAS_BIAS) v += bias[n];
                if (ACT == 1) v = (v > 20.f) ? v : log1pf(__expf(v)); // softplus
                C[(size_t)m * ldc + n] = v;
            }
        }
    }
}

// z_last[b][j] = emb[b, L-1, :] . in_proj_w[DI + j, :]
__global__ __launch_bounds__(256)
void zlast_kernel(const float* __restrict__ emb, const float* __restrict__ in_proj,
                  float* __restrict__ zlast) {
    const int wave = threadIdx.x >> 6, lane = threadIdx.x & 63;
    const int j = blockIdx.x * 4 + wave;
    const int b = blockIdx.y;
    const float* e = emb + ((size_t)b * Ln + (Ln - 1)) * DMn;
    const float* w = in_proj + (size_t)(DIn + j) * DMn;
    float s = 0.f;
    for (int k = lane; k < DMn; k += 64) s += e[k] * w[k];
    for (int off = 32; off > 0; off >>= 1) s += __shfl_down(s, off);
    if (lane == 0) zlast[(size_t)b * DIn + j] = s;
}

// C_last[b][s] = u[b, L-1, :] . x_proj_w[80 + s, :]
__global__ __launch_bounds__(64)
void clast_kernel(const float* __restrict__ u, const float* __restrict__ x_proj,
                  float* __restrict__ Clast) {
    const int s_idx = blockIdx.x, b = blockIdx.y, lane = threadIdx.x;
    const float* ur = u + ((size_t)b * Ln + (Ln - 1)) * DIn;
    const float* w = x_proj + (size_t)(XPW + s_idx) * DIn;
    float s = 0.f;
    for (int k = lane; k < DIn; k += 64) s += ur[k] * w[k];
    for (int off = 32; off > 0; off >>= 1) s += __shfl_down(s, off);
    if (lane == 0) Clast[b * DSn + s_idx] = s;
}

// causal depthwise conv (DC=4) + bias + silu
__global__ __launch_bounds__(256)
void conv_silu_kernel(const float* __restrict__ upre, const float* __restrict__ cw,
                      const float* __restrict__ cb, float* __restrict__ u) {
    const size_t idx = (size_t)blockIdx.x * 256 + threadIdx.x;
    const int d = (int)(idx & (DIn - 1));
    const int t = (int)((idx >> 11) & (Ln - 1));
    float s = cb[d];
    #pragma unroll
    for (int j = 0; j < DCn; ++j) {
        const int tt = t - (DCn - 1) + j;
        if (tt >= 0) s += upre[idx + (size_t)(j - (DCn - 1)) * DIn] * cw[d * DCn + j];
    }
    u[idx] = silu_(s);
}

// per (b, d, chunk): run the exact recurrence from h=0 over CHUNK steps; record h and sum(delta)
__global__ __launch_bounds__(256)
void scan_chunk_kernel(const float* __restrict__ delta, const float* __restrict__ u,
                       const float* __restrict__ dtB, const float* __restrict__ A_log,
                       float* __restrict__ cS, float* __restrict__ cH) {
    const int d = blockIdx.x * 256 + threadIdx.x;
    const int c = blockIdx.y, b = blockIdx.z;
    float A[DSn], h[DSn];
    const float4* al = (const float4*)(A_log + (size_t)d * DSn);
    #pragma unroll
    for (int q = 0; q < 4; ++q) {
        const float4 v = al[q];
        A[q * 4 + 0] = -__expf(v.x); A[q * 4 + 1] = -__expf(v.y);
        A[q * 4 + 2] = -__expf(v.z); A[q * 4 + 3] = -__expf(v.w);
        h[q * 4 + 0] = 0.f; h[q * 4 + 1] = 0.f; h[q * 4 + 2] = 0.f; h[q * 4 + 3] = 0.f;
    }
    float Ssum = 0.f;
    const size_t base = ((size_t)b * Ln + (size_t)c * CHUNK) * DIn + d;
    const float* Bp = dtB + ((size_t)b * Ln + (size_t)c * CHUNK) * XPW + DTRn;
    for (int tt = 0; tt < CHUNK; ++tt) {
        const float dl = delta[base + (size_t)tt * DIn];
        const float uu = u[base + (size_t)tt * DIn];
        const float du = dl * uu;
        Ssum += dl;
        const float4 b0 = *(const float4*)(Bp + tt * XPW);
        const float4 b1 = *(const float4*)(Bp + tt * XPW + 4);
        const float4 b2 = *(const float4*)(Bp + tt * XPW + 8);
        const float4 b3 = *(const float4*)(Bp + tt * XPW + 12);
        const float Bv[DSn] = {b0.x, b0.y, b0.z, b0.w, b1.x, b1.y, b1.z, b1.w,
                               b2.x, b2.y, b2.z, b2.w, b3.x, b3.y, b3.z, b3.w};
        #pragma unroll
        for (int s = 0; s < DSn; ++s) h[s] = __expf(dl * A[s]) * h[s] + du * Bv[s];
    }
    const size_t cidx = ((size_t)b * NCHUNK + c) * DIn + d;
    cS[cidx] = Ssum;
    float4* outp = (float4*)(cH + cidx * DSn);
    outp[0] = float4{h[0], h[1], h[2], h[3]};
    outp[1] = float4{h[4], h[5], h[6], h[7]};
    outp[2] = float4{h[8], h[9], h[10], h[11]};
    outp[3] = float4{h[12], h[13], h[14], h[15]};
}

// fold chunks in time order, then produce gated y_last[b][d]
__global__ __launch_bounds__(256)
void combine_kernel(const float* __restrict__ cS, const float* __restrict__ cH,
                    const float* __restrict__ A_log, const float* __restrict__ Clast,
                    const float* __restrict__ Dp, const float* __restrict__ u,
                    const float* __restrict__ zlast, float* __restrict__ ylast) {
    const int d = blockIdx.x * 256 + threadIdx.x;
    const int b = blockIdx.y;
    float A[DSn], h[DSn];
    const float4* al = (const float4*)(A_log + (size_t)d * DSn);
    #pragma unroll
    for (int q = 0; q < 4; ++q) {
        const float4 v = al[q];
        A[q * 4 + 0] = -__expf(v.x); A[q * 4 + 1] = -__expf(v.y);
        A[q * 4 + 2] = -__expf(v.z); A[q * 4 + 3] = -__expf(v.w);
        h[q * 4 + 0] = 0.f; h[q * 4 + 1] = 0.f; h[q * 4 + 2] = 0.f; h[q * 4 + 3] = 0.f;
    }
    for (int c = 0; c < NCHUNK; ++c) {
        const size_t cidx = ((size_t)b * NCHUNK + c) * DIn + d;
        const float Sc = cS[cidx];
        const float4* hp = (const float4*)(cH + cidx * DSn);
        const float4 h0 = hp[0], h1 = hp[1], h2 = hp[2], h3 = hp[3];
        const float hc[DSn] = {h0.x, h0.y, h0.z, h0.w, h1.x, h1.y, h1.z, h1.w,
                               h2.x, h2.y, h2.z, h2.w, h3.x, h3.y, h3.z, h3.w};
        #pragma unroll
        for (int s = 0; s < DSn; ++s) h[s] = __expf(A[s] * Sc) * h[s] + hc[s];
    }
    float y = 0.f;
    #pragma unroll
    for (int s = 0; s < DSn; ++s) y += h[s] * Clast[b * DSn + s];
    const float ul = u[((size_t)b * Ln + (Ln - 1)) * DIn + d];
    y += Dp[d] * ul;
    const float z = zlast[(size_t)b * DIn + d];
    y *= silu_(z);
    ylast[(size_t)b * DIn + d] = y;
}

// w_eff[d] = sum_m fc_w[m] * out_proj_w[m][d]
__global__ __launch_bounds__(256)
void weff_kernel(const float* __restrict__ fc_w, const float* __restrict__ out_w,
                 float* __restrict__ weff) {
    const int d = blockIdx.x * 256 + threadIdx.x;
    float s = 0.f;
    for (int m = 0; m < DMn; ++m) s += fc_w[m] * out_w[(size_t)m * DIn + d];
    weff[d] = s;
}

// out[b] = fc_b + sum_d ylast[b][d] * w_eff[d]
__global__ __launch_bounds__(256)
void final_kernel(const float* __restrict__ ylast, const float* __restrict__ weff,
                  const float* __restrict__ fc_b, float* __restrict__ out) {
    const int b = blockIdx.x, tid = threadIdx.x;
    __shared__ float red[256];
    float s = 0.f;
    for (int d = tid; d < DIn; d += 256) s += ylast[(size_t)b * DIn + d] * weff[d];
    red[tid] = s;
    __syncthreads();
    for (int off = 128; off > 0; off >>= 1) {
        if (tid < off) red[tid] += red[tid + off];
        __syncthreads();
    }
    if (tid == 0) out[b] = red[0] + fc_b[0];
}

} // namespace

extern "C" void kernel_launch(void* const* d_in, const int* in_sizes, int n_in,
                              void* d_out, int out_size, void* d_ws, size_t ws_size,
                              hipStream_t stream) {
    (void)in_sizes; (void)n_in; (void)out_size; (void)ws_size;
    const float* x       = (const float*)d_in[0];
    const float* W_emb   = (const float*)d_in[1];
    const float* b_emb   = (const float*)d_in[2];
    const float* in_proj = (const float*)d_in[3];
    const float* conv_w  = (const float*)d_in[4];
    const float* conv_b  = (const float*)d_in[5];
    const float* x_proj  = (const float*)d_in[6];
    const float* dt_w    = (const float*)d_in[7];
    const float* dt_b    = (const float*)d_in[8];
    const float* A_log   = (const float*)d_in[9];
    const float* Dp      = (const float*)d_in[10];
    const float* out_w   = (const float*)d_in[11];
    const float* fc_w    = (const float*)d_in[12];
    const float* fc_b    = (const float*)d_in[13];
    float* out = (float*)d_out;
    float* ws  = (float*)d_ws;

    const size_t ML = (size_t)Bn * Ln; // 4096
    float* emb   = ws;                  // 4096*1024   (reused for chunk bufs later)
    float* upre  = emb + ML * DMn;      // 4096*2048   (reused for delta later)
    float* u     = upre + ML * DIn;     // 4096*2048
    float* dtB   = u + ML * DIn;        // 4096*80
    float* zlast = dtB + ML * XPW;      // 4*2048
    float* Clast = zlast + (size_t)Bn * DIn; // 64
    float* ylast = Clast + Bn * DSn;    // 4*2048
    float* weff  = ylast + (size_t)Bn * DIn; // 2048
    float* cS    = emb;                               // 4*16*2048
    float* cH    = emb + (size_t)Bn * NCHUNK * DIn;   // 4*16*2048*16
    float* delta = upre;

    // 1. emb = x @ W_emb^T + b_emb            [4096, 1024]
    gemm_nt<0, true><<<dim3(DMn / TILE, ML / TILE), 256, 0, stream>>>(
        x, INn, W_emb, INn, b_emb, emb, DMn, DMn, INn);
    // 2. z_last (only last timestep of z is ever used)
    zlast_kernel<<<dim3(DIn / 4, Bn), 256, 0, stream>>>(emb, in_proj, zlast);
    // 3. u_pre = emb @ in_proj_w[0:DI]^T      [4096, 2048]
    gemm_nt<0, false><<<dim3(DIn / TILE, ML / TILE), 256, 0, stream>>>(
        emb, DMn, in_proj, DMn, nullptr, upre, DIn, DIn, DMn);
    // 4. u = silu(causal depthwise conv(u_pre) + conv_b)
    conv_silu_kernel<<<(unsigned)((ML * DIn) / 256), 256, 0, stream>>>(upre, conv_w, conv_b, u);
    // 5. dtB = u @ x_proj_w[0:80]^T           [4096, 80] (dt | B)
    gemm_nt<0, false><<<dim3((XPW + TILE - 1) / TILE, ML / TILE), 256, 0, stream>>>(
        u, DIn, x_proj, DIn, nullptr, dtB, XPW, XPW, DIn);
    // 6. C_last (only last timestep of C is ever used)
    clast_kernel<<<dim3(DSn, Bn), 64, 0, stream>>>(u, x_proj, Clast);
    // 7. delta = softplus(dt @ dt_proj_w^T + dt_proj_b)   [4096, 2048] (into u_pre buf)
    gemm_nt<1, true><<<dim3(DIn / TILE, ML / TILE), 256, 0, stream>>>(
        dtB, XPW, dt_w, DTRn, dt_b, delta, DIn, DIn, DTRn);
    // 8. chunked scan (exact recurrence per 64-step chunk)
    scan_chunk_kernel<<<dim3(DIn / 256, NCHUNK, Bn), 256, 0, stream>>>(
        delta, u, dtB, A_log, cS, cH);
    // 9. fold chunks + C-readout + D-skip + silu(z) gate
    combine_kernel<<<dim3(DIn / 256, Bn), 256, 0, stream>>>(
        cS, cH, A_log, Clast, Dp, u, zlast, ylast);
    // 10. w_eff = fc_w @ out_proj_w  (fold the two output projections)
    weff_kernel<<<DIn / 256, 256, 0, stream>>>(fc_w, out_w, weff);
    // 11. out[b] = y_last[b] . w_eff + fc_b
    final_kernel<<<Bn, 256, 0, stream>>>(ylast, weff, fc_b, out);
}

// Round 2
// 284.045 us; speedup vs baseline: 1.9960x; 1.9960x over previous
//
#include <hip/hip_runtime.h>
#include <cstddef>
#include <cstdint>

namespace {

typedef _Float16 half8 __attribute__((ext_vector_type(8)));
typedef _Float16 half4 __attribute__((ext_vector_type(4)));
typedef float f32x4 __attribute__((ext_vector_type(4)));

constexpr int Bn   = 4;
constexpr int Ln   = 1024;
constexpr int INn  = 256;
constexpr int DMn  = 1024;
constexpr int DSn  = 16;
constexpr int DCn  = 4;
constexpr int DIn  = 2048;
constexpr int DTRn = 64;
constexpr int XPW  = DTRn + DSn;   // 80
constexpr int NCHUNK = 16;
constexpr int CHUNK  = Ln / NCHUNK; // 64

__device__ __forceinline__ float silu_(float x) { return x / (1.f + __expf(-x)); }

// ---------------- fp32 -> fp16 converters ----------------
__global__ __launch_bounds__(256)
void f2h_kernel(const float* __restrict__ in, _Float16* __restrict__ out, int n4) {
    const int i = blockIdx.x * 256 + threadIdx.x;
    if (i < n4) {
        const float4 v = ((const float4*)in)[i];
        ((half4*)out)[i] = half4{(_Float16)v.x, (_Float16)v.y, (_Float16)v.z, (_Float16)v.w};
    }
}

// x_proj rows 0..79 -> fp16 padded to 128 rows (zeros beyond)
__global__ __launch_bounds__(256)
void padcvt_xproj(const float* __restrict__ in, _Float16* __restrict__ out) {
    const int i = blockIdx.x * 256 + threadIdx.x;   // half4 units over [128][2048]
    const int r = i >> 9;          // 2048/4 = 512 per row
    const int c4 = i & 511;
    half4 h;
    if (r < XPW) {
        const float4 v = ((const float4*)(in + (size_t)r * DIn))[c4];
        h = half4{(_Float16)v.x, (_Float16)v.y, (_Float16)v.z, (_Float16)v.w};
    } else {
        h = half4{(_Float16)0.f, (_Float16)0.f, (_Float16)0.f, (_Float16)0.f};
    }
    ((half4*)(out + (size_t)r * DIn))[c4] = h;
}

// ---------------- MFMA fp16 GEMM: C[m][n] = act(A[m][:].B[n][:] + bias[n]) ----------------
// A [M][K] fp16 row-major lda, Bw [N][K] fp16 row-major ldb (i.e. B^T input).
// Block tile 128x128, 4 waves each 64x64, BK=32, global_load_lds staging (m97 structure).
template<int ACT, bool HAS_BIAS, bool H_OUT>
__global__ __launch_bounds__(256)
void hgemm(const _Float16* __restrict__ A, int lda,
           const _Float16* __restrict__ Bw, int ldb,
           const float* __restrict__ bias,
           float* __restrict__ C, _Float16* __restrict__ Ch, int ldc,
           int N, int K) {
    __shared__ _Float16 As[128 * 32];
    __shared__ _Float16 Bs[128 * 32];
    const int tid  = threadIdx.x;
    const int lane = tid & 63, wid = tid >> 6;
    const int wm = wid >> 1, wn = wid & 1;
    const int m0 = blockIdx.y * 128, n0 = blockIdx.x * 128;

    f32x4 acc[4][4] = {};

    for (int k0 = 0; k0 < K; k0 += 32) {
        #pragma unroll
        for (int i = 0; i < 2; ++i) {
            const int off = tid * 16 + i * 4096;   // byte offset within 8 KB tile
            const int row = off >> 6;              // 64 B per LDS row (32 halves)
            const int ch  = (off & 63) >> 1;       // half offset within row
            const _Float16* ga = A  + (size_t)(m0 + row) * lda + k0 + ch;
            const _Float16* gb = Bw + (size_t)(n0 + row) * ldb + k0 + ch;
            __builtin_amdgcn_global_load_lds(
                (const __attribute__((address_space(1))) void*)ga,
                (__attribute__((address_space(3))) void*)(&As[off >> 1]), 16, 0, 0);
            __builtin_amdgcn_global_load_lds(
                (const __attribute__((address_space(1))) void*)gb,
                (__attribute__((address_space(3))) void*)(&Bs[off >> 1]), 16, 0, 0);
        }
        __syncthreads();   // drains vmcnt (global_load_lds) for all waves

        const int ar = lane & 15;
        const int kq = (lane >> 4) * 8;
        half8 af[4], bf[4];
        #pragma unroll
        for (int i = 0; i < 4; ++i)
            af[i] = *(const half8*)&As[(wm * 64 + i * 16 + ar) * 32 + kq];
        #pragma unroll
        for (int j = 0; j < 4; ++j)
            bf[j] = *(const half8*)&Bs[(wn * 64 + j * 16 + ar) * 32 + kq];
        #pragma unroll
        for (int i = 0; i < 4; ++i)
            #pragma unroll
            for (int j = 0; j < 4; ++j)
                acc[i][j] = __builtin_amdgcn_mfma_f32_16x16x32_f16(af[i], bf[j], acc[i][j], 0, 0, 0);
        __syncthreads();   // all waves done reading before next stage overwrites
    }

    const int cr = (lane >> 4) * 4;   // C/D: col = lane&15, row = (lane>>4)*4 + r
    const int cn = lane & 15;
    #pragma unroll
    for (int i = 0; i < 4; ++i) {
        #pragma unroll
        for (int j = 0; j < 4; ++j) {
            const int n = n0 + wn * 64 + j * 16 + cn;
            if (n < N) {
                #pragma unroll
                for (int r = 0; r < 4; ++r) {
                    const int m = m0 + wm * 64 + i * 16 + cr + r;
                    float v = acc[i][j][r];
                    if (HAS_BIAS) v += bias[n];
                    if (ACT == 1) v = (v > 20.f) ? v : log1pf(__expf(v)); // softplus
                    C[(size_t)m * ldc + n] = v;
                    if (H_OUT) Ch[(size_t)m * ldc + n] = (_Float16)v;
                }
            }
        }
    }
}

// ---------------- z_last[b][j] = emb[b, L-1, :] . in_proj_w[DI + j, :] (fp32) ----------------
__global__ __launch_bounds__(256)
void zlast_kernel(const float* __restrict__ emb, const float* __restrict__ in_proj,
                  float* __restrict__ zlast) {
    const int wave = threadIdx.x >> 6, lane = threadIdx.x & 63;
    const int j = blockIdx.x * 4 + wave;
    const int b = blockIdx.y;
    const float* e = emb + ((size_t)b * Ln + (Ln - 1)) * DMn;
    const float* w = in_proj + (size_t)(DIn + j) * DMn;
    float s = 0.f;
    for (int k = lane; k < DMn; k += 64) s += e[k] * w[k];
    for (int off = 32; off > 0; off >>= 1) s += __shfl_down(s, off);
    if (lane == 0) zlast[(size_t)b * DIn + j] = s;
}

// ---------------- C_last[b][s] = u[b, L-1, :] . x_proj_w[80 + s, :] ----------------
__global__ __launch_bounds__(64)
void clast_kernel(const _Float16* __restrict__ u, const float* __restrict__ x_proj,
                  float* __restrict__ Clast) {
    const int s_idx = blockIdx.x, b = blockIdx.y, lane = threadIdx.x;
    const _Float16* ur = u + ((size_t)b * Ln + (Ln - 1)) * DIn;
    const float* w = x_proj + (size_t)(XPW + s_idx) * DIn;
    float s = 0.f;
    for (int k = lane; k < DIn; k += 64) s += (float)ur[k] * w[k];
    for (int off = 32; off > 0; off >>= 1) s += __shfl_down(s, off);
    if (lane == 0) Clast[b * DSn + s_idx] = s;
}

// ---------------- causal depthwise conv (DC=4) + bias + silu -> fp16 u ----------------
__global__ __launch_bounds__(256)
void conv_silu_kernel(const float* __restrict__ upre, const float* __restrict__ cw,
                      const float* __restrict__ cb, _Float16* __restrict__ uh) {
    const size_t idx = (size_t)blockIdx.x * 256 + threadIdx.x;
    const int d = (int)(idx & (DIn - 1));
    const int t = (int)((idx >> 11) & (Ln - 1));
    float s = cb[d];
    #pragma unroll
    for (int j = 0; j < DCn; ++j) {
        const int tt = t - (DCn - 1) + j;
        if (tt >= 0) s += upre[idx + (size_t)(j - (DCn - 1)) * DIn] * cw[d * DCn + j];
    }
    uh[idx] = (_Float16)silu_(s);
}

// ---------------- chunked scan ----------------
__global__ __launch_bounds__(256)
void scan_chunk_kernel(const float* __restrict__ delta, const _Float16* __restrict__ u,
                       const float* __restrict__ dtB, const float* __restrict__ A_log,
                       float* __restrict__ cS, float* __restrict__ cH) {
    const int d = blockIdx.x * 256 + threadIdx.x;
    const int c = blockIdx.y, b = blockIdx.z;
    float A[DSn], h[DSn];
    const float4* al = (const float4*)(A_log + (size_t)d * DSn);
    #pragma unroll
    for (int q = 0; q < 4; ++q) {
        const float4 v = al[q];
        A[q * 4 + 0] = -__expf(v.x); A[q * 4 + 1] = -__expf(v.y);
        A[q * 4 + 2] = -__expf(v.z); A[q * 4 + 3] = -__expf(v.w);
        h[q * 4 + 0] = 0.f; h[q * 4 + 1] = 0.f; h[q * 4 + 2] = 0.f; h[q * 4 + 3] = 0.f;
    }
    float Ssum = 0.f;
    const size_t base = ((size_t)b * Ln + (size_t)c * CHUNK) * DIn + d;
    const float* Bp = dtB + ((size_t)b * Ln + (size_t)c * CHUNK) * XPW + DTRn;
    for (int tt = 0; tt < CHUNK; ++tt) {
        const float dl = delta[base + (size_t)tt * DIn];
        const float uu = (float)u[base + (size_t)tt * DIn];
        const float du = dl * uu;
        Ssum += dl;
        const float4 b0 = *(const float4*)(Bp + tt * XPW);
        const float4 b1 = *(const float4*)(Bp + tt * XPW + 4);
        const float4 b2 = *(const float4*)(Bp + tt * XPW + 8);
        const float4 b3 = *(const float4*)(Bp + tt * XPW + 12);
        const float Bv[DSn] = {b0.x, b0.y, b0.z, b0.w, b1.x, b1.y, b1.z, b1.w,
                               b2.x, b2.y, b2.z, b2.w, b3.x, b3.y, b3.z, b3.w};
        #pragma unroll
        for (int s = 0; s < DSn; ++s) h[s] = __expf(dl * A[s]) * h[s] + du * Bv[s];
    }
    const size_t cidx = ((size_t)b * NCHUNK + c) * DIn + d;
    cS[cidx] = Ssum;
    float4* outp = (float4*)(cH + cidx * DSn);
    outp[0] = float4{h[0], h[1], h[2], h[3]};
    outp[1] = float4{h[4], h[5], h[6], h[7]};
    outp[2] = float4{h[8], h[9], h[10], h[11]};
    outp[3] = float4{h[12], h[13], h[14], h[15]};
}

// ---------------- fold chunks + C-readout + D-skip + silu(z) gate ----------------
__global__ __launch_bounds__(256)
void combine_kernel(const float* __restrict__ cS, const float* __restrict__ cH,
                    const float* __restrict__ A_log, const float* __restrict__ Clast,
                    const float* __restrict__ Dp, const _Float16* __restrict__ u,
                    const float* __restrict__ zlast, float* __restrict__ ylast) {
    const int d = blockIdx.x * 256 + threadIdx.x;
    const int b = blockIdx.y;
    float A[DSn], h[DSn];
    const float4* al = (const float4*)(A_log + (size_t)d * DSn);
    #pragma unroll
    for (int q = 0; q < 4; ++q) {
        const float4 v = al[q];
        A[q * 4 + 0] = -__expf(v.x); A[q * 4 + 1] = -__expf(v.y);
        A[q * 4 + 2] = -__expf(v.z); A[q * 4 + 3] = -__expf(v.w);
        h[q * 4 + 0] = 0.f; h[q * 4 + 1] = 0.f; h[q * 4 + 2] = 0.f; h[q * 4 + 3] = 0.f;
    }
    for (int c = 0; c < NCHUNK; ++c) {
        const size_t cidx = ((size_t)b * NCHUNK + c) * DIn + d;
        const float Sc = cS[cidx];
        const float4* hp = (const float4*)(cH + cidx * DSn);
        const float4 h0 = hp[0], h1 = hp[1], h2 = hp[2], h3 = hp[3];
        const float hc[DSn] = {h0.x, h0.y, h0.z, h0.w, h1.x, h1.y, h1.z, h1.w,
                               h2.x, h2.y, h2.z, h2.w, h3.x, h3.y, h3.z, h3.w};
        #pragma unroll
        for (int s = 0; s < DSn; ++s) h[s] = __expf(A[s] * Sc) * h[s] + hc[s];
    }
    float y = 0.f;
    #pragma unroll
    for (int s = 0; s < DSn; ++s) y += h[s] * Clast[b * DSn + s];
    const float ul = (float)u[((size_t)b * Ln + (Ln - 1)) * DIn + d];
    y += Dp[d] * ul;
    const float z = zlast[(size_t)b * DIn + d];
    y *= silu_(z);
    ylast[(size_t)b * DIn + d] = y;
}

// ---------------- w_eff[d] = sum_m fc_w[m] * out_proj_w[m][d] ----------------
__global__ __launch_bounds__(256)
void weff_kernel(const float* __restrict__ fc_w, const float* __restrict__ out_w,
                 float* __restrict__ weff) {
    const int d = blockIdx.x * 256 + threadIdx.x;
    float s = 0.f;
    for (int m = 0; m < DMn; ++m) s += fc_w[m] * out_w[(size_t)m * DIn + d];
    weff[d] = s;
}

// ---------------- out[b] = fc_b + sum_d ylast[b][d] * w_eff[d] ----------------
__global__ __launch_bounds__(256)
void final_kernel(const float* __restrict__ ylast, const float* __restrict__ weff,
                  const float* __restrict__ fc_b, float* __restrict__ out) {
    const int b = blockIdx.x, tid = threadIdx.x;
    __shared__ float red[256];
    float s = 0.f;
    for (int d = tid; d < DIn; d += 256) s += ylast[(size_t)b * DIn + d] * weff[d];
    red[tid] = s;
    __syncthreads();
    for (int off = 128; off > 0; off >>= 1) {
        if (tid < off) red[tid] += red[tid + off];
        __syncthreads();
    }
    if (tid == 0) out[b] = red[0] + fc_b[0];
}

} // namespace

extern "C" void kernel_launch(void* const* d_in, const int* in_sizes, int n_in,
                              void* d_out, int out_size, void* d_ws, size_t ws_size,
                              hipStream_t stream) {
    (void)in_sizes; (void)n_in; (void)out_size; (void)ws_size;
    const float* x       = (const float*)d_in[0];
    const float* W_emb   = (const float*)d_in[1];
    const float* b_emb   = (const float*)d_in[2];
    const float* in_proj = (const float*)d_in[3];
    const float* conv_w  = (const float*)d_in[4];
    const float* conv_b  = (const float*)d_in[5];
    const float* x_proj  = (const float*)d_in[6];
    const float* dt_w    = (const float*)d_in[7];
    const float* dt_b    = (const float*)d_in[8];
    const float* A_log   = (const float*)d_in[9];
    const float* Dp      = (const float*)d_in[10];
    const float* out_w   = (const float*)d_in[11];
    const float* fc_w    = (const float*)d_in[12];
    const float* fc_b    = (const float*)d_in[13];
    float* out = (float*)d_out;
    char* w8 = (char*)d_ws;

    const size_t MB = 1ull << 20;
    // lifetimes: emb[emb GEMM..zlast] then cS/cH[scan..combine] share region 0
    float*    emb    = (float*)(w8);                      // 16 MB
    float*    upre   = (float*)(w8 + 16 * MB);            // 32 MB (delta aliases after conv)
    _Float16* uh     = (_Float16*)(w8 + 48 * MB);         // 16 MB
    _Float16* embh   = (_Float16*)(w8 + 64 * MB);         //  8 MB
    float*    dtB    = (float*)(w8 + 72 * MB);            // 1.3125 MB
    _Float16* dtBh   = (_Float16*)(w8 + 72 * MB + 1310720);        // 0.625 MB
    _Float16* xh     = (_Float16*)(w8 + 72 * MB + 1310720 + 655360);       // 2 MB
    char*     w8b    = w8 + 72 * MB + 1310720 + 655360 + 2 * MB;
    _Float16* W_embh = (_Float16*)(w8b);                  // 0.5 MB
    _Float16* in_projh = (_Float16*)(w8b + 524288);       // 4 MB
    _Float16* x_projh  = (_Float16*)(w8b + 524288 + 4 * MB);       // 0.5 MB (padded 128 rows)
    _Float16* dt_wh    = (_Float16*)(w8b + 1048576 + 4 * MB);      // 0.25 MB
    float*    zlast  = (float*)(w8b + 1048576 + 4 * MB + 262144);
    float*    Clast  = zlast + (size_t)Bn * DIn;
    float*    ylast  = Clast + Bn * DSn;
    float*    weff   = ylast + (size_t)Bn * DIn;
    float*    cS     = emb;                               // after emb is dead
    float*    cH     = emb + (size_t)Bn * NCHUNK * DIn;
    float*    delta  = upre;                              // after upre is dead

    const size_t ML = (size_t)Bn * Ln; // 4096

    // 0. fp16 conversions (weights + input)
    f2h_kernel<<<(ML * INn / 4 + 255) / 256, 256, 0, stream>>>(x, xh, (int)(ML * INn / 4));
    f2h_kernel<<<(DMn * INn / 4 + 255) / 256, 256, 0, stream>>>(W_emb, W_embh, DMn * INn / 4);
    f2h_kernel<<<((size_t)DIn * DMn / 4 + 255) / 256, 256, 0, stream>>>(in_proj, in_projh, DIn * DMn / 4);
    padcvt_xproj<<<128 * 512 / 256, 256, 0, stream>>>(x_proj, x_projh);
    f2h_kernel<<<(DIn * DTRn / 4 + 255) / 256, 256, 0, stream>>>(dt_w, dt_wh, DIn * DTRn / 4);

    // 1. emb = x @ W_emb^T + b_emb  (fp32 out for zlast, fp16 mirror for next GEMM)
    hgemm<0, true, true><<<dim3(DMn / 128, ML / 128), 256, 0, stream>>>(
        xh, INn, W_embh, INn, b_emb, emb, embh, DMn, DMn, INn);
    // 2. z_last
    zlast_kernel<<<dim3(DIn / 4, Bn), 256, 0, stream>>>(emb, in_proj, zlast);
    // 3. u_pre = emb @ in_proj_w[0:DI]^T
    hgemm<0, false, false><<<dim3(DIn / 128, ML / 128), 256, 0, stream>>>(
        embh, DMn, in_projh, DMn, nullptr, upre, nullptr, DIn, DIn, DMn);
    // 4. u = silu(conv(u_pre) + conv_b)  -> fp16
    conv_silu_kernel<<<(unsigned)((ML * DIn) / 256), 256, 0, stream>>>(upre, conv_w, conv_b, uh);
    // 5. dtB = u @ x_proj_w[0:80]^T  (fp32 for scan B, fp16 mirror for dt GEMM)
    hgemm<0, false, true><<<dim3(1, ML / 128), 256, 0, stream>>>(
        uh, DIn, x_projh, DIn, nullptr, dtB, dtBh, XPW, XPW, DIn);
    // 6. C_last
    clast_kernel<<<dim3(DSn, Bn), 64, 0, stream>>>(uh, x_proj, Clast);
    // 7. delta = softplus(dt @ dt_proj_w^T + dt_proj_b)
    hgemm<1, true, false><<<dim3(DIn / 128, ML / 128), 256, 0, stream>>>(
        dtBh, XPW, dt_wh, DTRn, dt_b, delta, nullptr, DIn, DIn, DTRn);
    // 8. chunked scan
    scan_chunk_kernel<<<dim3(DIn / 256, NCHUNK, Bn), 256, 0, stream>>>(
        delta, uh, dtB, A_log, cS, cH);
    // 9. combine + gate
    combine_kernel<<<dim3(DIn / 256, Bn), 256, 0, stream>>>(
        cS, cH, A_log, Clast, Dp, uh, zlast, ylast);
    // 10. w_eff
    weff_kernel<<<DIn / 256, 256, 0, stream>>>(fc_w, out_w, weff);
    // 11. out
    final_kernel<<<Bn, 256, 0, stream>>>(ylast, weff, fc_b, out);
}

// Round 3
// 227.080 us; speedup vs baseline: 2.4968x; 1.2509x over previous
//
#include <hip/hip_runtime.h>
#include <cstddef>
#include <cstdint>

namespace {

typedef _Float16 half8 __attribute__((ext_vector_type(8)));
typedef _Float16 half4 __attribute__((ext_vector_type(4)));
typedef float f32x4 __attribute__((ext_vector_type(4)));

constexpr int Bn   = 4;
constexpr int Ln   = 1024;
constexpr int INn  = 256;
constexpr int DMn  = 1024;
constexpr int DSn  = 16;
constexpr int DCn  = 4;
constexpr int DIn  = 2048;
constexpr int DTRn = 64;
constexpr int XPW  = DTRn + DSn;   // 80
constexpr int NCHUNK = 16;
constexpr int CHUNK  = Ln / NCHUNK; // 64
constexpr int SKn  = 8;             // split-K factor for the skinny dtB GEMM
constexpr int KCn  = DIn / SKn;     // 256
constexpr int WCH  = 32;            // weff m-chunks

__device__ __forceinline__ float silu_(float x) { return x / (1.f + __expf(-x)); }

// ---------------- fp32 -> fp16 converters ----------------
__global__ __launch_bounds__(256)
void f2h_kernel(const float* __restrict__ in, _Float16* __restrict__ out, int n4) {
    const int i = blockIdx.x * 256 + threadIdx.x;
    if (i < n4) {
        const float4 v = ((const float4*)in)[i];
        ((half4*)out)[i] = half4{(_Float16)v.x, (_Float16)v.y, (_Float16)v.z, (_Float16)v.w};
    }
}

// x_proj rows 0..79 -> fp16 padded to 128 rows (zeros beyond)
__global__ __launch_bounds__(256)
void padcvt_xproj(const float* __restrict__ in, _Float16* __restrict__ out) {
    const int i = blockIdx.x * 256 + threadIdx.x;   // half4 units over [128][2048]
    const int r = i >> 9;
    const int c4 = i & 511;
    half4 h;
    if (r < XPW) {
        const float4 v = ((const float4*)(in + (size_t)r * DIn))[c4];
        h = half4{(_Float16)v.x, (_Float16)v.y, (_Float16)v.z, (_Float16)v.w};
    } else {
        h = half4{(_Float16)0.f, (_Float16)0.f, (_Float16)0.f, (_Float16)0.f};
    }
    ((half4*)(out + (size_t)r * DIn))[c4] = h;
}

// ---------------- MFMA fp16 GEMM (128x128 tile, 4 waves, BK=32, global_load_lds) ----------
// OUT: 0 = fp32 C, 1 = fp16 Ch, 2 = both
template<int ACT, bool HAS_BIAS, int OUT>
__global__ __launch_bounds__(256)
void hgemm(const _Float16* __restrict__ A, int lda,
           const _Float16* __restrict__ Bw, int ldb,
           const float* __restrict__ bias,
           float* __restrict__ C, _Float16* __restrict__ Ch, int ldc,
           int N, int K) {
    __shared__ _Float16 As[128 * 32];
    __shared__ _Float16 Bs[128 * 32];
    const int tid  = threadIdx.x;
    const int lane = tid & 63, wid = tid >> 6;
    const int wm = wid >> 1, wn = wid & 1;
    const int m0 = blockIdx.y * 128, n0 = blockIdx.x * 128;

    f32x4 acc[4][4] = {};

    for (int k0 = 0; k0 < K; k0 += 32) {
        #pragma unroll
        for (int i = 0; i < 2; ++i) {
            const int off = tid * 16 + i * 4096;
            const int row = off >> 6;
            const int ch  = (off & 63) >> 1;
            const _Float16* ga = A  + (size_t)(m0 + row) * lda + k0 + ch;
            const _Float16* gb = Bw + (size_t)(n0 + row) * ldb + k0 + ch;
            __builtin_amdgcn_global_load_lds(
                (const __attribute__((address_space(1))) void*)ga,
                (__attribute__((address_space(3))) void*)(&As[off >> 1]), 16, 0, 0);
            __builtin_amdgcn_global_load_lds(
                (const __attribute__((address_space(1))) void*)gb,
                (__attribute__((address_space(3))) void*)(&Bs[off >> 1]), 16, 0, 0);
        }
        __syncthreads();

        const int ar = lane & 15;
        const int kq = (lane >> 4) * 8;
        half8 af[4], bf[4];
        #pragma unroll
        for (int i = 0; i < 4; ++i)
            af[i] = *(const half8*)&As[(wm * 64 + i * 16 + ar) * 32 + kq];
        #pragma unroll
        for (int j = 0; j < 4; ++j)
            bf[j] = *(const half8*)&Bs[(wn * 64 + j * 16 + ar) * 32 + kq];
        #pragma unroll
        for (int i = 0; i < 4; ++i)
            #pragma unroll
            for (int j = 0; j < 4; ++j)
                acc[i][j] = __builtin_amdgcn_mfma_f32_16x16x32_f16(af[i], bf[j], acc[i][j], 0, 0, 0);
        __syncthreads();
    }

    const int cr = (lane >> 4) * 4;
    const int cn = lane & 15;
    #pragma unroll
    for (int i = 0; i < 4; ++i) {
        #pragma unroll
        for (int j = 0; j < 4; ++j) {
            const int n = n0 + wn * 64 + j * 16 + cn;
            if (n < N) {
                #pragma unroll
                for (int r = 0; r < 4; ++r) {
                    const int m = m0 + wm * 64 + i * 16 + cr + r;
                    float v = acc[i][j][r];
                    if (HAS_BIAS) v += bias[n];
                    if (ACT == 1) v = (v > 20.f) ? v : log1pf(__expf(v)); // softplus
                    if (OUT == 0 || OUT == 2) C[(size_t)m * ldc + n] = v;
                    if (OUT >= 1) Ch[(size_t)m * ldc + n] = (_Float16)v;
                }
            }
        }
    }
}

// ---------------- split-K skinny GEMM: P[sk][m][n<80] = uh[m][kc] . xp[n][kc] --------------
__global__ __launch_bounds__(256)
void skgemm(const _Float16* __restrict__ A, const _Float16* __restrict__ Bw,
            float* __restrict__ P) {
    __shared__ _Float16 As[128 * 32];
    __shared__ _Float16 Bs[128 * 32];
    const int tid  = threadIdx.x;
    const int lane = tid & 63, wid = tid >> 6;
    const int wm = wid >> 1, wn = wid & 1;
    const int m0 = blockIdx.y * 128;
    const int sk = blockIdx.x;

    f32x4 acc[4][4] = {};
    const int kbeg = sk * KCn;
    for (int k0 = kbeg; k0 < kbeg + KCn; k0 += 32) {
        #pragma unroll
        for (int i = 0; i < 2; ++i) {
            const int off = tid * 16 + i * 4096;
            const int row = off >> 6;
            const int ch  = (off & 63) >> 1;
            const _Float16* ga = A  + (size_t)(m0 + row) * DIn + k0 + ch;
            const _Float16* gb = Bw + (size_t)row * DIn + k0 + ch;
            __builtin_amdgcn_global_load_lds(
                (const __attribute__((address_space(1))) void*)ga,
                (__attribute__((address_space(3))) void*)(&As[off >> 1]), 16, 0, 0);
            __builtin_amdgcn_global_load_lds(
                (const __attribute__((address_space(1))) void*)gb,
                (__attribute__((address_space(3))) void*)(&Bs[off >> 1]), 16, 0, 0);
        }
        __syncthreads();
        const int ar = lane & 15;
        const int kq = (lane >> 4) * 8;
        half8 af[4], bf[4];
        #pragma unroll
        for (int i = 0; i < 4; ++i)
            af[i] = *(const half8*)&As[(wm * 64 + i * 16 + ar) * 32 + kq];
        #pragma unroll
        for (int j = 0; j < 4; ++j)
            bf[j] = *(const half8*)&Bs[(wn * 64 + j * 16 + ar) * 32 + kq];
        #pragma unroll
        for (int i = 0; i < 4; ++i)
            #pragma unroll
            for (int j = 0; j < 4; ++j)
                acc[i][j] = __builtin_amdgcn_mfma_f32_16x16x32_f16(af[i], bf[j], acc[i][j], 0, 0, 0);
        __syncthreads();
    }

    const int cr = (lane >> 4) * 4;
    const int cn = lane & 15;
    #pragma unroll
    for (int i = 0; i < 4; ++i) {
        #pragma unroll
        for (int j = 0; j < 4; ++j) {
            const int n = wn * 64 + j * 16 + cn;
            if (n < XPW) {
                #pragma unroll
                for (int r = 0; r < 4; ++r) {
                    const int m = m0 + wm * 64 + i * 16 + cr + r;
                    P[((size_t)sk * (Bn * Ln) + m) * XPW + n] = acc[i][j][r];
                }
            }
        }
    }
}

__global__ __launch_bounds__(256)
void skcombine(const float* __restrict__ P, _Float16* __restrict__ dtBh) {
    const int i = blockIdx.x * 256 + threadIdx.x;   // over ML*80
    float s = 0.f;
    #pragma unroll
    for (int sk = 0; sk < SKn; ++sk) s += P[(size_t)sk * (Bn * Ln) * XPW + i];
    dtBh[i] = (_Float16)s;
}

// ---------------- z_last[b][j] = embh[b, L-1, :] . in_proj_w[DI + j, :] ----------------
__global__ __launch_bounds__(256)
void zlast_kernel(const _Float16* __restrict__ embh, const float* __restrict__ in_proj,
                  float* __restrict__ zlast) {
    const int wave = threadIdx.x >> 6, lane = threadIdx.x & 63;
    const int j = blockIdx.x * 4 + wave;
    const int b = blockIdx.y;
    const _Float16* e = embh + ((size_t)b * Ln + (Ln - 1)) * DMn;
    const float* w = in_proj + (size_t)(DIn + j) * DMn;
    float s = 0.f;
    for (int k = lane; k < DMn; k += 64) s += (float)e[k] * w[k];
    for (int off = 32; off > 0; off >>= 1) s += __shfl_down(s, off);
    if (lane == 0) zlast[(size_t)b * DIn + j] = s;
}

// ---------------- C_last[b][s] = u[b, L-1, :] . x_proj_w[80 + s, :] ----------------
__global__ __launch_bounds__(64)
void clast_kernel(const _Float16* __restrict__ u, const float* __restrict__ x_proj,
                  float* __restrict__ Clast) {
    const int s_idx = blockIdx.x, b = blockIdx.y, lane = threadIdx.x;
    const _Float16* ur = u + ((size_t)b * Ln + (Ln - 1)) * DIn;
    const float* w = x_proj + (size_t)(XPW + s_idx) * DIn;
    float s = 0.f;
    for (int k = lane; k < DIn; k += 64) s += (float)ur[k] * w[k];
    for (int off = 32; off > 0; off >>= 1) s += __shfl_down(s, off);
    if (lane == 0) Clast[b * DSn + s_idx] = s;
}

// ---------------- causal depthwise conv (DC=4) + bias + silu (fp16 in/out) ----------------
__global__ __launch_bounds__(256)
void conv_silu_kernel(const _Float16* __restrict__ upre, const float* __restrict__ cw,
                      const float* __restrict__ cb, _Float16* __restrict__ uh) {
    const size_t idx = (size_t)blockIdx.x * 256 + threadIdx.x;
    const int d = (int)(idx & (DIn - 1));
    const int t = (int)((idx >> 11) & (Ln - 1));
    float s = cb[d];
    #pragma unroll
    for (int j = 0; j < DCn; ++j) {
        const int tt = t - (DCn - 1) + j;
        if (tt >= 0) s += (float)upre[idx + (size_t)(j - (DCn - 1)) * DIn] * cw[d * DCn + j];
    }
    uh[idx] = (_Float16)silu_(s);
}

// ---------------- chunked scan ----------------
__global__ __launch_bounds__(256)
void scan_chunk_kernel(const _Float16* __restrict__ delta, const _Float16* __restrict__ u,
                       const _Float16* __restrict__ dtBh, const float* __restrict__ A_log,
                       float* __restrict__ cS, float* __restrict__ cH) {
    const int d = blockIdx.x * 256 + threadIdx.x;
    const int c = blockIdx.y, b = blockIdx.z;
    float A[DSn], h[DSn];
    const float4* al = (const float4*)(A_log + (size_t)d * DSn);
    #pragma unroll
    for (int q = 0; q < 4; ++q) {
        const float4 v = al[q];
        A[q * 4 + 0] = -__expf(v.x); A[q * 4 + 1] = -__expf(v.y);
        A[q * 4 + 2] = -__expf(v.z); A[q * 4 + 3] = -__expf(v.w);
        h[q * 4 + 0] = 0.f; h[q * 4 + 1] = 0.f; h[q * 4 + 2] = 0.f; h[q * 4 + 3] = 0.f;
    }
    float Ssum = 0.f;
    const size_t base = ((size_t)b * Ln + (size_t)c * CHUNK) * DIn + d;
    const _Float16* Bp = dtBh + ((size_t)b * Ln + (size_t)c * CHUNK) * XPW + DTRn;
    for (int tt = 0; tt < CHUNK; ++tt) {
        const float dl = (float)delta[base + (size_t)tt * DIn];
        const float uu = (float)u[base + (size_t)tt * DIn];
        const float du = dl * uu;
        Ssum += dl;
        const half8 bv0 = *(const half8*)(Bp + tt * XPW);
        const half8 bv1 = *(const half8*)(Bp + tt * XPW + 8);
        float Bv[DSn];
        #pragma unroll
        for (int q = 0; q < 8; ++q) { Bv[q] = (float)bv0[q]; Bv[8 + q] = (float)bv1[q]; }
        #pragma unroll
        for (int s = 0; s < DSn; ++s) h[s] = __expf(dl * A[s]) * h[s] + du * Bv[s];
    }
    const size_t cidx = ((size_t)b * NCHUNK + c) * DIn + d;
    cS[cidx] = Ssum;
    float4* outp = (float4*)(cH + cidx * DSn);
    outp[0] = float4{h[0], h[1], h[2], h[3]};
    outp[1] = float4{h[4], h[5], h[6], h[7]};
    outp[2] = float4{h[8], h[9], h[10], h[11]};
    outp[3] = float4{h[12], h[13], h[14], h[15]};
}

// ---------------- fold chunks + C-readout + D-skip + silu(z) gate ----------------
__global__ __launch_bounds__(256)
void combine_kernel(const float* __restrict__ cS, const float* __restrict__ cH,
                    const float* __restrict__ A_log, const float* __restrict__ Clast,
                    const float* __restrict__ Dp, const _Float16* __restrict__ u,
                    const float* __restrict__ zlast, float* __restrict__ ylast) {
    const int d = blockIdx.x * 256 + threadIdx.x;
    const int b = blockIdx.y;
    float A[DSn], h[DSn];
    const float4* al = (const float4*)(A_log + (size_t)d * DSn);
    #pragma unroll
    for (int q = 0; q < 4; ++q) {
        const float4 v = al[q];
        A[q * 4 + 0] = -__expf(v.x); A[q * 4 + 1] = -__expf(v.y);
        A[q * 4 + 2] = -__expf(v.z); A[q * 4 + 3] = -__expf(v.w);
        h[q * 4 + 0] = 0.f; h[q * 4 + 1] = 0.f; h[q * 4 + 2] = 0.f; h[q * 4 + 3] = 0.f;
    }
    for (int c = 0; c < NCHUNK; ++c) {
        const size_t cidx = ((size_t)b * NCHUNK + c) * DIn + d;
        const float Sc = cS[cidx];
        const float4* hp = (const float4*)(cH + cidx * DSn);
        const float4 h0 = hp[0], h1 = hp[1], h2 = hp[2], h3 = hp[3];
        const float hc[DSn] = {h0.x, h0.y, h0.z, h0.w, h1.x, h1.y, h1.z, h1.w,
                               h2.x, h2.y, h2.z, h2.w, h3.x, h3.y, h3.z, h3.w};
        #pragma unroll
        for (int s = 0; s < DSn; ++s) h[s] = __expf(A[s] * Sc) * h[s] + hc[s];
    }
    float y = 0.f;
    #pragma unroll
    for (int s = 0; s < DSn; ++s) y += h[s] * Clast[b * DSn + s];
    const float ul = (float)u[((size_t)b * Ln + (Ln - 1)) * DIn + d];
    y += Dp[d] * ul;
    const float z = zlast[(size_t)b * DIn + d];
    y *= silu_(z);
    ylast[(size_t)b * DIn + d] = y;
}

// ---------------- weff partials: wp[c][d] = sum_{m in chunk c} fc_w[m]*out_w[m][d] -------
__global__ __launch_bounds__(256)
void weff_part(const float* __restrict__ fc_w, const float* __restrict__ out_w,
               float* __restrict__ wp) {
    const int d = blockIdx.x * 256 + threadIdx.x;
    const int c = blockIdx.y;
    const int mstep = DMn / WCH; // 32
    float s = 0.f;
    for (int m = c * mstep; m < (c + 1) * mstep; ++m) s += fc_w[m] * out_w[(size_t)m * DIn + d];
    wp[(size_t)c * DIn + d] = s;
}

// ---------------- out[b] = fc_b + sum_d ylast[b][d] * sum_c wp[c][d] ----------------
__global__ __launch_bounds__(256)
void final_kernel(const float* __restrict__ ylast, const float* __restrict__ wp,
                  const float* __restrict__ fc_b, float* __restrict__ out) {
    const int b = blockIdx.x, tid = threadIdx.x;
    __shared__ float red[256];
    float s = 0.f;
    for (int d = tid; d < DIn; d += 256) {
        float w = 0.f;
        #pragma unroll
        for (int c = 0; c < WCH; ++c) w += wp[(size_t)c * DIn + d];
        s += ylast[(size_t)b * DIn + d] * w;
    }
    red[tid] = s;
    __syncthreads();
    for (int off = 128; off > 0; off >>= 1) {
        if (tid < off) red[tid] += red[tid + off];
        __syncthreads();
    }
    if (tid == 0) out[b] = red[0] + fc_b[0];
}

} // namespace

extern "C" void kernel_launch(void* const* d_in, const int* in_sizes, int n_in,
                              void* d_out, int out_size, void* d_ws, size_t ws_size,
                              hipStream_t stream) {
    (void)in_sizes; (void)n_in; (void)out_size; (void)ws_size;
    const float* x       = (const float*)d_in[0];
    const float* W_emb   = (const float*)d_in[1];
    const float* b_emb   = (const float*)d_in[2];
    const float* in_proj = (const float*)d_in[3];
    const float* conv_w  = (const float*)d_in[4];
    const float* conv_b  = (const float*)d_in[5];
    const float* x_proj  = (const float*)d_in[6];
    const float* dt_w    = (const float*)d_in[7];
    const float* dt_b    = (const float*)d_in[8];
    const float* A_log   = (const float*)d_in[9];
    const float* Dp      = (const float*)d_in[10];
    const float* out_w   = (const float*)d_in[11];
    const float* fc_w    = (const float*)d_in[12];
    const float* fc_b    = (const float*)d_in[13];
    float* out = (float*)d_out;
    char* w8 = (char*)d_ws;

    const size_t MB = 1ull << 20;
    _Float16* embh     = (_Float16*)(w8);            // 8 MB
    _Float16* upreh    = (_Float16*)(w8 + 8 * MB);   // 16 MB
    _Float16* uh       = (_Float16*)(w8 + 24 * MB);  // 16 MB
    _Float16* deltah   = (_Float16*)(w8 + 40 * MB);  // 16 MB
    float*    skp      = (float*)(w8 + 56 * MB);     // 10 MB (dead after skcombine)
    float*    cS       = skp;                        // aliases skp: 0.5 MB
    float*    cH       = skp + (size_t)Bn * NCHUNK * DIn;  // 8 MB
    _Float16* dtBh     = (_Float16*)(w8 + 66 * MB);  // 0.64 MB
    _Float16* xh       = (_Float16*)(w8 + 67 * MB);  // 2 MB
    _Float16* W_embh   = (_Float16*)(w8 + 69 * MB);  // 0.5 MB
    _Float16* in_projh = (_Float16*)(w8 + 70 * MB);  // 4 MB
    _Float16* xp_h     = (_Float16*)(w8 + 74 * MB);  // 0.5 MB (padded to 128 rows)
    _Float16* dt_wh    = (_Float16*)(w8 + 75 * MB);  // 0.25 MB
    float*    wp       = (float*)(w8 + 76 * MB);     // 0.25 MB
    float*    zlast    = (float*)(w8 + 77 * MB);
    float*    Clast    = zlast + (size_t)Bn * DIn;
    float*    ylast    = Clast + Bn * DSn;

    const size_t ML = (size_t)Bn * Ln; // 4096

    // 0. fp16 conversions
    f2h_kernel<<<(unsigned)(ML * INn / 4 / 256), 256, 0, stream>>>(x, xh, (int)(ML * INn / 4));
    f2h_kernel<<<DMn * INn / 4 / 256, 256, 0, stream>>>(W_emb, W_embh, DMn * INn / 4);
    f2h_kernel<<<DIn * DMn / 4 / 256, 256, 0, stream>>>(in_proj, in_projh, DIn * DMn / 4);
    padcvt_xproj<<<128 * 512 / 256, 256, 0, stream>>>(x_proj, xp_h);
    f2h_kernel<<<DIn * DTRn / 4 / 256, 256, 0, stream>>>(dt_w, dt_wh, DIn * DTRn / 4);
    // weff partials (independent of everything else)
    weff_part<<<dim3(DIn / 256, WCH), 256, 0, stream>>>(fc_w, out_w, wp);

    // 1. embh = fp16(x @ W_emb^T + b_emb)
    hgemm<0, true, 1><<<dim3(DMn / 128, ML / 128), 256, 0, stream>>>(
        xh, INn, W_embh, INn, b_emb, nullptr, embh, DMn, DMn, INn);
    // 2. z_last
    zlast_kernel<<<dim3(DIn / 4, Bn), 256, 0, stream>>>(embh, in_proj, zlast);
    // 3. upreh = fp16(embh @ in_proj_w[0:DI]^T)
    hgemm<0, false, 1><<<dim3(DIn / 128, ML / 128), 256, 0, stream>>>(
        embh, DMn, in_projh, DMn, nullptr, nullptr, upreh, DIn, DIn, DMn);
    // 4. uh = fp16(silu(conv(upreh) + conv_b))
    conv_silu_kernel<<<(unsigned)((ML * DIn) / 256), 256, 0, stream>>>(upreh, conv_w, conv_b, uh);
    // 5. dtB = uh @ x_proj_w[0:80]^T via split-K partials, then combine -> fp16
    skgemm<<<dim3(SKn, ML / 128), 256, 0, stream>>>(uh, xp_h, skp);
    skcombine<<<(unsigned)(ML * XPW / 256), 256, 0, stream>>>(skp, dtBh);
    // 6. C_last
    clast_kernel<<<dim3(DSn, Bn), 64, 0, stream>>>(uh, x_proj, Clast);
    // 7. deltah = fp16(softplus(dt @ dt_proj_w^T + dt_proj_b))
    hgemm<1, true, 1><<<dim3(DIn / 128, ML / 128), 256, 0, stream>>>(
        dtBh, XPW, dt_wh, DTRn, dt_b, nullptr, deltah, DIn, DIn, DTRn);
    // 8. chunked scan (cS/cH alias skp region, dead by now)
    scan_chunk_kernel<<<dim3(DIn / 256, NCHUNK, Bn), 256, 0, stream>>>(
        deltah, uh, dtBh, A_log, cS, cH);
    // 9. combine + gate
    combine_kernel<<<dim3(DIn / 256, Bn), 256, 0, stream>>>(
        cS, cH, A_log, Clast, Dp, uh, zlast, ylast);
    // 10. out
    final_kernel<<<Bn, 256, 0, stream>>>(ylast, wp, fc_b, out);
}

// Round 4
// 185.936 us; speedup vs baseline: 3.0492x; 1.2213x over previous
//
#include <hip/hip_runtime.h>
#include <cstddef>
#include <cstdint>

namespace {

typedef _Float16 half8 __attribute__((ext_vector_type(8)));
typedef _Float16 half4 __attribute__((ext_vector_type(4)));
typedef float f32x4 __attribute__((ext_vector_type(4)));

constexpr int Bn   = 4;
constexpr int Ln   = 1024;
constexpr int INn  = 256;
constexpr int DMn  = 1024;
constexpr int DSn  = 16;
constexpr int DCn  = 4;
constexpr int DIn  = 2048;
constexpr int DTRn = 64;
constexpr int XPW  = DTRn + DSn;    // 80
constexpr int NCHUNK = 16;
constexpr int CHUNK  = Ln / NCHUNK; // 64
constexpr int WCH  = 32;            // weff m-chunks
constexpr int ML   = Bn * Ln;       // 4096

__device__ __forceinline__ float silu_(float x) { return x / (1.f + __expf(-x)); }

// ---------------- fused fp32->fp16 converter: x, in_proj(full 4096 rows), dt_w ----------
__global__ __launch_bounds__(256)
void prep_f2h(const float* __restrict__ x, _Float16* __restrict__ xh,
              const float* __restrict__ ip, _Float16* __restrict__ iph,
              const float* __restrict__ dtw, _Float16* __restrict__ dtwh) {
    const int bid = blockIdx.x, tid = threadIdx.x;
    const float* in; _Float16* out; int i;
    if (bid < 1024)      { in = x;   out = xh;   i = bid * 256 + tid; }          // 262144 quads
    else if (bid < 5120) { in = ip;  out = iph;  i = (bid - 1024) * 256 + tid; } // 1048576 quads
    else                 { in = dtw; out = dtwh; i = (bid - 5120) * 256 + tid; } // 32768 quads
    const float4 v = ((const float4*)in)[i];
    ((half4*)out)[i] = half4{(_Float16)v.x, (_Float16)v.y, (_Float16)v.z, (_Float16)v.w};
}

// ---------------- W_emb [1024][256] fp32 -> W_embT [256][1024] fp16 (LDS tile) ----------
__global__ __launch_bounds__(256)
void transp_cvt(const float* __restrict__ in, _Float16* __restrict__ out) {
    __shared__ float tile[32][33];
    const int m0 = blockIdx.x * 32, c0 = blockIdx.y * 32;
    const int lc = threadIdx.x & 31, lr = threadIdx.x >> 5; // lr 0..7
    #pragma unroll
    for (int ph = 0; ph < 4; ++ph)
        tile[lr + ph * 8][lc] = in[(size_t)(m0 + lr + ph * 8) * INn + c0 + lc];
    __syncthreads();
    #pragma unroll
    for (int ph = 0; ph < 4; ++ph)
        out[(size_t)(c0 + lr + ph * 8) * DMn + m0 + lc] = (_Float16)tile[lc][lr + ph * 8];
}

// x_proj rows 0..79 -> fp16 padded to 128 rows (zeros beyond)
__global__ __launch_bounds__(256)
void padcvt_xproj(const float* __restrict__ in, _Float16* __restrict__ out) {
    const int i = blockIdx.x * 256 + threadIdx.x;
    const int r = i >> 9;
    const int c4 = i & 511;
    half4 h;
    if (r < XPW) {
        const float4 v = ((const float4*)(in + (size_t)r * DIn))[c4];
        h = half4{(_Float16)v.x, (_Float16)v.y, (_Float16)v.z, (_Float16)v.w};
    } else {
        h = half4{(_Float16)0.f, (_Float16)0.f, (_Float16)0.f, (_Float16)0.f};
    }
    ((half4*)(out + (size_t)r * DIn))[c4] = h;
}

// ---------------- badd[n] = in_projh[n][:].b_emb  (n over 4096) ----------------
__global__ __launch_bounds__(256)
void badd_kernel(const _Float16* __restrict__ iph, const float* __restrict__ b_emb,
                 float* __restrict__ badd) {
    const int wave = threadIdx.x >> 6, lane = threadIdx.x & 63;
    const int n = blockIdx.x * 4 + wave;
    const _Float16* row = iph + (size_t)n * DMn;
    float s = 0.f;
    #pragma unroll
    for (int half8i = 0; half8i < 2; ++half8i) {
        const half8 v = *(const half8*)(row + half8i * 512 + lane * 8);
        #pragma unroll
        for (int q = 0; q < 8; ++q) s += (float)v[q] * b_emb[half8i * 512 + lane * 8 + q];
    }
    for (int off = 32; off > 0; off >>= 1) s += __shfl_down(s, off);
    if (lane == 0) badd[n] = s;
}

// ---------------- generic split-K MFMA GEMM -> fp32 partials ----------------
// grid (SK, Mtiles, Ntiles). P[sk][m][n], row stride N. A [M][lda], Bw [.][ldb] fp16.
__global__ __launch_bounds__(256)
void skgemm2(const _Float16* __restrict__ A, int lda,
             const _Float16* __restrict__ Bw, int ldb,
             float* __restrict__ P, int N, int Kc) {
    __shared__ _Float16 As[128 * 32];
    __shared__ _Float16 Bs[128 * 32];
    const int tid  = threadIdx.x;
    const int lane = tid & 63, wid = tid >> 6;
    const int wm = wid >> 1, wn = wid & 1;
    const int sk = blockIdx.x;
    const int m0 = blockIdx.y * 128;
    const int n0 = blockIdx.z * 128;
    const int M  = gridDim.y * 128;

    f32x4 acc[4][4] = {};
    const int kbeg = sk * Kc;
    for (int k0 = kbeg; k0 < kbeg + Kc; k0 += 32) {
        #pragma unroll
        for (int i = 0; i < 2; ++i) {
            const int off = tid * 16 + i * 4096;
            const int row = off >> 6;
            const int ch  = (off & 63) >> 1;
            const _Float16* ga = A  + (size_t)(m0 + row) * lda + k0 + ch;
            const _Float16* gb = Bw + (size_t)(n0 + row) * ldb + k0 + ch;
            __builtin_amdgcn_global_load_lds(
                (const __attribute__((address_space(1))) void*)ga,
                (__attribute__((address_space(3))) void*)(&As[off >> 1]), 16, 0, 0);
            __builtin_amdgcn_global_load_lds(
                (const __attribute__((address_space(1))) void*)gb,
                (__attribute__((address_space(3))) void*)(&Bs[off >> 1]), 16, 0, 0);
        }
        __syncthreads();
        const int ar = lane & 15;
        const int kq = (lane >> 4) * 8;
        half8 af[4], bf[4];
        #pragma unroll
        for (int i = 0; i < 4; ++i)
            af[i] = *(const half8*)&As[(wm * 64 + i * 16 + ar) * 32 + kq];
        #pragma unroll
        for (int j = 0; j < 4; ++j)
            bf[j] = *(const half8*)&Bs[(wn * 64 + j * 16 + ar) * 32 + kq];
        #pragma unroll
        for (int i = 0; i < 4; ++i)
            #pragma unroll
            for (int j = 0; j < 4; ++j)
                acc[i][j] = __builtin_amdgcn_mfma_f32_16x16x32_f16(af[i], bf[j], acc[i][j], 0, 0, 0);
        __syncthreads();
    }

    const int cr = (lane >> 4) * 4;
    const int cn = lane & 15;
    #pragma unroll
    for (int i = 0; i < 4; ++i) {
        #pragma unroll
        for (int j = 0; j < 4; ++j) {
            const int n = n0 + wn * 64 + j * 16 + cn;
            if (n < N) {
                #pragma unroll
                for (int r = 0; r < 4; ++r) {
                    const int m = m0 + wm * 64 + i * 16 + cr + r;
                    P[((size_t)sk * M + m) * N + n] = acc[i][j][r];
                }
            }
        }
    }
}

// sum split-K partials -> fp16
__global__ __launch_bounds__(256)
void skcomb(const float* __restrict__ P, _Float16* __restrict__ out, int total, int nsk) {
    const int i = blockIdx.x * 256 + threadIdx.x;
    if (i >= total) return;
    float s = 0.f;
    for (int k = 0; k < nsk; ++k) s += P[(size_t)k * total + i];
    out[i] = (_Float16)s;
}

// ---------------- MFMA fp16 GEMM (128x128 tile, 4 waves, BK=32) ----------
template<int ACT, bool HAS_BIAS>
__global__ __launch_bounds__(256)
void hgemm(const _Float16* __restrict__ A, int lda,
           const _Float16* __restrict__ Bw, int ldb,
           const float* __restrict__ bias,
           _Float16* __restrict__ Ch, int ldc,
           int N, int K) {
    __shared__ _Float16 As[128 * 32];
    __shared__ _Float16 Bs[128 * 32];
    const int tid  = threadIdx.x;
    const int lane = tid & 63, wid = tid >> 6;
    const int wm = wid >> 1, wn = wid & 1;
    const int m0 = blockIdx.y * 128, n0 = blockIdx.x * 128;

    f32x4 acc[4][4] = {};

    for (int k0 = 0; k0 < K; k0 += 32) {
        #pragma unroll
        for (int i = 0; i < 2; ++i) {
            const int off = tid * 16 + i * 4096;
            const int row = off >> 6;
            const int ch  = (off & 63) >> 1;
            const _Float16* ga = A  + (size_t)(m0 + row) * lda + k0 + ch;
            const _Float16* gb = Bw + (size_t)(n0 + row) * ldb + k0 + ch;
            __builtin_amdgcn_global_load_lds(
                (const __attribute__((address_space(1))) void*)ga,
                (__attribute__((address_space(3))) void*)(&As[off >> 1]), 16, 0, 0);
            __builtin_amdgcn_global_load_lds(
                (const __attribute__((address_space(1))) void*)gb,
                (__attribute__((address_space(3))) void*)(&Bs[off >> 1]), 16, 0, 0);
        }
        __syncthreads();

        const int ar = lane & 15;
        const int kq = (lane >> 4) * 8;
        half8 af[4], bf[4];
        #pragma unroll
        for (int i = 0; i < 4; ++i)
            af[i] = *(const half8*)&As[(wm * 64 + i * 16 + ar) * 32 + kq];
        #pragma unroll
        for (int j = 0; j < 4; ++j)
            bf[j] = *(const half8*)&Bs[(wn * 64 + j * 16 + ar) * 32 + kq];
        #pragma unroll
        for (int i = 0; i < 4; ++i)
            #pragma unroll
            for (int j = 0; j < 4; ++j)
                acc[i][j] = __builtin_amdgcn_mfma_f32_16x16x32_f16(af[i], bf[j], acc[i][j], 0, 0, 0);
        __syncthreads();
    }

    const int cr = (lane >> 4) * 4;
    const int cn = lane & 15;
    #pragma unroll
    for (int i = 0; i < 4; ++i) {
        #pragma unroll
        for (int j = 0; j < 4; ++j) {
            const int n = n0 + wn * 64 + j * 16 + cn;
            if (n < N) {
                #pragma unroll
                for (int r = 0; r < 4; ++r) {
                    const int m = m0 + wm * 64 + i * 16 + cr + r;
                    float v = acc[i][j][r];
                    if (HAS_BIAS) v += bias[n];
                    if (ACT == 1) v = (v > 20.f) ? v : log1pf(__expf(v)); // softplus
                    Ch[(size_t)m * ldc + n] = (_Float16)v;
                }
            }
        }
    }
}

// ---------------- z_last[b][j] = x[b,L-1,:].Wfold_z[j][:] + badd[DI+j] ----------------
__global__ __launch_bounds__(256)
void zlast_fold(const float* __restrict__ x, const _Float16* __restrict__ Wfh,
                const float* __restrict__ badd, float* __restrict__ zlast) {
    const int wave = threadIdx.x >> 6, lane = threadIdx.x & 63;
    const int j = blockIdx.x * 4 + wave;
    const int b = blockIdx.y;
    const float* xr = x + ((size_t)b * Ln + (Ln - 1)) * INn;
    const _Float16* w = Wfh + (size_t)(DIn + j) * INn;
    const half4 wv = *(const half4*)(w + lane * 4);
    const float4 xv = *(const float4*)(xr + lane * 4);
    float s = (float)wv[0] * xv.x + (float)wv[1] * xv.y + (float)wv[2] * xv.z + (float)wv[3] * xv.w;
    for (int off = 32; off > 0; off >>= 1) s += __shfl_down(s, off);
    if (lane == 0) zlast[(size_t)b * DIn + j] = s + badd[DIn + j];
}

// ---------------- C_last[b][s] = u[b, L-1, :] . x_proj_w[80 + s, :] ----------------
__global__ __launch_bounds__(64)
void clast_kernel(const _Float16* __restrict__ u, const float* __restrict__ x_proj,
                  float* __restrict__ Clast) {
    const int s_idx = blockIdx.x, b = blockIdx.y, lane = threadIdx.x;
    const _Float16* ur = u + ((size_t)b * Ln + (Ln - 1)) * DIn;
    const float* w = x_proj + (size_t)(XPW + s_idx) * DIn;
    float s = 0.f;
    for (int k = lane; k < DIn; k += 64) s += (float)ur[k] * w[k];
    for (int off = 32; off > 0; off >>= 1) s += __shfl_down(s, off);
    if (lane == 0) Clast[b * DSn + s_idx] = s;
}

// ---------------- conv+silu vectorized: 8 d (half8) x 4 t per thread ----------------
__global__ __launch_bounds__(256)
void conv_silu_v2(const _Float16* __restrict__ upre, const float* __restrict__ cw,
                  const float* __restrict__ cb, _Float16* __restrict__ uh) {
    const int tid = threadIdx.x;
    const int dg = tid;                 // d-group 0..255 within block
    const int tg = blockIdx.x;          // 0..1023
    const int b  = tg >> 8;
    const int t0 = (tg & 255) * 4;
    const int d0 = dg * 8;
    const size_t rowbase = ((size_t)b * Ln + t0) * DIn + d0;

    half8 hzero;
    #pragma unroll
    for (int q = 0; q < 8; ++q) hzero[q] = (_Float16)0.f;

    half8 rows[7];
    if (t0 >= 3) {
        #pragma unroll
        for (int r = 0; r < 7; ++r)
            rows[r] = *(const half8*)(upre + rowbase + (ptrdiff_t)(r - 3) * DIn);
    } else {
        #pragma unroll
        for (int r = 0; r < 7; ++r) {
            const int t = t0 - 3 + r;
            rows[r] = (t >= 0) ? *(const half8*)(upre + rowbase + (ptrdiff_t)(r - 3) * DIn) : hzero;
        }
    }

    f32x4 cwq[8];
    float cbv[8];
    #pragma unroll
    for (int q = 0; q < 8; ++q) {
        cwq[q] = *(const f32x4*)(cw + (size_t)(d0 + q) * DCn);
        cbv[q] = cb[d0 + q];
    }

    #pragma unroll
    for (int s = 0; s < 4; ++s) {
        half8 o;
        #pragma unroll
        for (int q = 0; q < 8; ++q) {
            float acc = cbv[q];
            #pragma unroll
            for (int j = 0; j < DCn; ++j) acc += (float)rows[s + j][q] * cwq[q][j];
            o[q] = (_Float16)silu_(acc);
        }
        *(half8*)(uh + rowbase + (size_t)s * DIn) = o;
    }
}

// ---------------- chunked scan ----------------
__global__ __launch_bounds__(256)
void scan_chunk_kernel(const _Float16* __restrict__ delta, const _Float16* __restrict__ u,
                       const _Float16* __restrict__ dtBh, const float* __restrict__ A_log,
                       float* __restrict__ cS, float* __restrict__ cH) {
    const int d = blockIdx.x * 256 + threadIdx.x;
    const int c = blockIdx.y, b = blockIdx.z;
    float A[DSn], h[DSn];
    const float4* al = (const float4*)(A_log + (size_t)d * DSn);
    #pragma unroll
    for (int q = 0; q < 4; ++q) {
        const float4 v = al[q];
        A[q * 4 + 0] = -__expf(v.x); A[q * 4 + 1] = -__expf(v.y);
        A[q * 4 + 2] = -__expf(v.z); A[q * 4 + 3] = -__expf(v.w);
        h[q * 4 + 0] = 0.f; h[q * 4 + 1] = 0.f; h[q * 4 + 2] = 0.f; h[q * 4 + 3] = 0.f;
    }
    float Ssum = 0.f;
    const size_t base = ((size_t)b * Ln + (size_t)c * CHUNK) * DIn + d;
    const _Float16* Bp = dtBh + ((size_t)b * Ln + (size_t)c * CHUNK) * XPW + DTRn;
    for (int tt = 0; tt < CHUNK; ++tt) {
        const float dl = (float)delta[base + (size_t)tt * DIn];
        const float uu = (float)u[base + (size_t)tt * DIn];
        const float du = dl * uu;
        Ssum += dl;
        const half8 bv0 = *(const half8*)(Bp + tt * XPW);
        const half8 bv1 = *(const half8*)(Bp + tt * XPW + 8);
        float Bv[DSn];
        #pragma unroll
        for (int q = 0; q < 8; ++q) { Bv[q] = (float)bv0[q]; Bv[8 + q] = (float)bv1[q]; }
        #pragma unroll
        for (int s = 0; s < DSn; ++s) h[s] = __expf(dl * A[s]) * h[s] + du * Bv[s];
    }
    const size_t cidx = ((size_t)b * NCHUNK + c) * DIn + d;
    cS[cidx] = Ssum;
    float4* outp = (float4*)(cH + cidx * DSn);
    outp[0] = float4{h[0], h[1], h[2], h[3]};
    outp[1] = float4{h[4], h[5], h[6], h[7]};
    outp[2] = float4{h[8], h[9], h[10], h[11]};
    outp[3] = float4{h[12], h[13], h[14], h[15]};
}

// ---------------- fold chunks + C-readout + D-skip + silu(z) gate ----------------
__global__ __launch_bounds__(256)
void combine_kernel(const float* __restrict__ cS, const float* __restrict__ cH,
                    const float* __restrict__ A_log, const float* __restrict__ Clast,
                    const float* __restrict__ Dp, const _Float16* __restrict__ u,
                    const float* __restrict__ zlast, float* __restrict__ ylast) {
    const int d = blockIdx.x * 256 + threadIdx.x;
    const int b = blockIdx.y;
    float A[DSn], h[DSn];
    const float4* al = (const float4*)(A_log + (size_t)d * DSn);
    #pragma unroll
    for (int q = 0; q < 4; ++q) {
        const float4 v = al[q];
        A[q * 4 + 0] = -__expf(v.x); A[q * 4 + 1] = -__expf(v.y);
        A[q * 4 + 2] = -__expf(v.z); A[q * 4 + 3] = -__expf(v.w);
        h[q * 4 + 0] = 0.f; h[q * 4 + 1] = 0.f; h[q * 4 + 2] = 0.f; h[q * 4 + 3] = 0.f;
    }
    for (int c = 0; c < NCHUNK; ++c) {
        const size_t cidx = ((size_t)b * NCHUNK + c) * DIn + d;
        const float Sc = cS[cidx];
        const float4* hp = (const float4*)(cH + cidx * DSn);
        const float4 h0 = hp[0], h1 = hp[1], h2 = hp[2], h3 = hp[3];
        const float hc[DSn] = {h0.x, h0.y, h0.z, h0.w, h1.x, h1.y, h1.z, h1.w,
                               h2.x, h2.y, h2.z, h2.w, h3.x, h3.y, h3.z, h3.w};
        #pragma unroll
        for (int s = 0; s < DSn; ++s) h[s] = __expf(A[s] * Sc) * h[s] + hc[s];
    }
    float y = 0.f;
    #pragma unroll
    for (int s = 0; s < DSn; ++s) y += h[s] * Clast[b * DSn + s];
    const float ul = (float)u[((size_t)b * Ln + (Ln - 1)) * DIn + d];
    y += Dp[d] * ul;
    const float z = zlast[(size_t)b * DIn + d];
    y *= silu_(z);
    ylast[(size_t)b * DIn + d] = y;
}

// ---------------- weff partials ----------------
__global__ __launch_bounds__(256)
void weff_part(const float* __restrict__ fc_w, const float* __restrict__ out_w,
               float* __restrict__ wp) {
    const int d = blockIdx.x * 256 + threadIdx.x;
    const int c = blockIdx.y;
    const int mstep = DMn / WCH; // 32
    float s = 0.f;
    for (int m = c * mstep; m < (c + 1) * mstep; ++m) s += fc_w[m] * out_w[(size_t)m * DIn + d];
    wp[(size_t)c * DIn + d] = s;
}

// ---------------- out[b] = fc_b + sum_d ylast[b][d] * sum_c wp[c][d] ----------------
__global__ __launch_bounds__(256)
void final_kernel(const float* __restrict__ ylast, const float* __restrict__ wp,
                  const float* __restrict__ fc_b, float* __restrict__ out) {
    const int b = blockIdx.x, tid = threadIdx.x;
    __shared__ float red[256];
    float s = 0.f;
    for (int d = tid; d < DIn; d += 256) {
        float w = 0.f;
        #pragma unroll
        for (int c = 0; c < WCH; ++c) w += wp[(size_t)c * DIn + d];
        s += ylast[(size_t)b * DIn + d] * w;
    }
    red[tid] = s;
    __syncthreads();
    for (int off = 128; off > 0; off >>= 1) {
        if (tid < off) red[tid] += red[tid + off];
        __syncthreads();
    }
    if (tid == 0) out[b] = red[0] + fc_b[0];
}

} // namespace

extern "C" void kernel_launch(void* const* d_in, const int* in_sizes, int n_in,
                              void* d_out, int out_size, void* d_ws, size_t ws_size,
                              hipStream_t stream) {
    (void)in_sizes; (void)n_in; (void)out_size; (void)ws_size;
    const float* x       = (const float*)d_in[0];
    const float* W_emb   = (const float*)d_in[1];
    const float* b_emb   = (const float*)d_in[2];
    const float* in_proj = (const float*)d_in[3];
    const float* conv_w  = (const float*)d_in[4];
    const float* conv_b  = (const float*)d_in[5];
    const float* x_proj  = (const float*)d_in[6];
    const float* dt_w    = (const float*)d_in[7];
    const float* dt_b    = (const float*)d_in[8];
    const float* A_log   = (const float*)d_in[9];
    const float* Dp      = (const float*)d_in[10];
    const float* out_w   = (const float*)d_in[11];
    const float* fc_w    = (const float*)d_in[12];
    const float* fc_b    = (const float*)d_in[13];
    float* out = (float*)d_out;
    char* w8 = (char*)d_ws;

    const size_t MB = 1ull << 20;
    _Float16* upreh    = (_Float16*)(w8);            // 16 MB [step u_pre -> conv]
    _Float16* uh       = (_Float16*)(w8 + 16 * MB);  // 16 MB [conv -> scan/combine/clast]
    // region A (17 MB): wfold partials (16 MB, early) then deltah (16 MB, late)
    float*    wfoldP   = (float*)(w8 + 32 * MB);
    _Float16* deltah   = (_Float16*)(w8 + 32 * MB);
    // region B (10.5 MB): dtB split-K partials then cS/cH
    float*    skp      = (float*)(w8 + 49 * MB);
    float*    cS       = skp;
    float*    cH       = skp + (size_t)Bn * NCHUNK * DIn;
    _Float16* dtBh     = (_Float16*)(w8 + 60 * MB);  // 0.64 MB
    _Float16* xh       = (_Float16*)(w8 + 61 * MB);  // 2 MB
    _Float16* W_embT_h = (_Float16*)(w8 + 63 * MB);  // 0.5 MB  [256][1024]
    _Float16* in_projh = (_Float16*)(w8 + 64 * MB);  // 8 MB (full 4096 rows)
    _Float16* xp_h     = (_Float16*)(w8 + 72 * MB);  // 0.5 MB (padded 128 rows)
    _Float16* dt_wh    = (_Float16*)(w8 + 73 * MB);  // 0.25 MB
    _Float16* Wfoldh   = (_Float16*)(w8 + 74 * MB);  // 2 MB [4096][256]
    float*    wp       = (float*)(w8 + 76 * MB);     // 0.25 MB
    float*    badd     = (float*)(w8 + 77 * MB);     // 16 KB
    float*    zlast    = badd + 4096;
    float*    Clast    = zlast + (size_t)Bn * DIn;
    float*    ylast    = Clast + 256;

    // 0. conversions + independent prep
    prep_f2h<<<5248, 256, 0, stream>>>(x, xh, in_proj, in_projh, dt_w, dt_wh);
    transp_cvt<<<dim3(DMn / 32, INn / 32), 256, 0, stream>>>(W_emb, W_embT_h);
    padcvt_xproj<<<128 * 512 / 256, 256, 0, stream>>>(x_proj, xp_h);
    weff_part<<<dim3(DIn / 256, WCH), 256, 0, stream>>>(fc_w, out_w, wp);
    badd_kernel<<<4096 / 4, 256, 0, stream>>>(in_projh, b_emb, badd);

    // 1. WfoldFull = in_proj @ W_emb  [4096][256] (split-K 4 x Kc=256)
    skgemm2<<<dim3(4, ML / 128, 2), 256, 0, stream>>>(
        in_projh, DMn, W_embT_h, DMn, wfoldP, INn, 256);
    skcomb<<<(ML * INn + 255) / 256, 256, 0, stream>>>(wfoldP, Wfoldh, ML * INn, 4);

    // 2. upreh = fp16(x @ Wfold_u^T + badd_u)   K=256
    hgemm<0, true><<<dim3(DIn / 128, ML / 128), 256, 0, stream>>>(
        xh, INn, Wfoldh, INn, badd, upreh, DIn, DIn, INn);
    // 3. z_last from folded z-rows
    zlast_fold<<<dim3(DIn / 4, Bn), 256, 0, stream>>>(x, Wfoldh, badd, zlast);
    // 4. uh = fp16(silu(conv(upreh) + conv_b))
    conv_silu_v2<<<1024, 256, 0, stream>>>(upreh, conv_w, conv_b, uh);
    // 5. dtB = uh @ x_proj_w[0:80]^T (split-K 8 x Kc=256) -> fp16
    skgemm2<<<dim3(8, ML / 128, 1), 256, 0, stream>>>(uh, DIn, xp_h, DIn, skp, XPW, 256);
    skcomb<<<(ML * XPW + 255) / 256, 256, 0, stream>>>(skp, dtBh, ML * XPW, 8);
    // 6. C_last
    clast_kernel<<<dim3(DSn, Bn), 64, 0, stream>>>(uh, x_proj, Clast);
    // 7. deltah = fp16(softplus(dt @ dt_proj_w^T + dt_proj_b))  (region A: wfoldP dead)
    hgemm<1, true><<<dim3(DIn / 128, ML / 128), 256, 0, stream>>>(
        dtBh, XPW, dt_wh, DTRn, dt_b, deltah, DIn, DIn, DTRn);
    // 8. chunked scan (region B: skp dead)
    scan_chunk_kernel<<<dim3(DIn / 256, NCHUNK, Bn), 256, 0, stream>>>(
        deltah, uh, dtBh, A_log, cS, cH);
    // 9. combine + gate
    combine_kernel<<<dim3(DIn / 256, Bn), 256, 0, stream>>>(
        cS, cH, A_log, Clast, Dp, uh, zlast, ylast);
    // 10. out
    final_kernel<<<Bn, 256, 0, stream>>>(ylast, wp, fc_b, out);
}

// Round 5
// 149.253 us; speedup vs baseline: 3.7987x; 1.2458x over previous
//
#include <hip/hip_runtime.h>
#include <cstddef>
#include <cstdint>

namespace {

typedef _Float16 half8 __attribute__((ext_vector_type(8)));
typedef _Float16 half4 __attribute__((ext_vector_type(4)));
typedef float f32x4 __attribute__((ext_vector_type(4)));

constexpr int Bn   = 4;
constexpr int Ln   = 1024;
constexpr int INn  = 256;
constexpr int DMn  = 1024;
constexpr int DSn  = 16;
constexpr int DCn  = 4;
constexpr int DIn  = 2048;
constexpr int DTRn = 64;
constexpr int XPW  = DTRn + DSn;    // 80
constexpr int NCHUNK = 16;
constexpr int CHUNK  = Ln / NCHUNK; // 64
constexpr int WCH  = 32;            // weff m-chunks
constexpr int ML   = Bn * Ln;       // 4096

__device__ __forceinline__ float silu_(float x) { return x / (1.f + __expf(-x)); }
// stable fast softplus: max(x,0) + log(1+exp(-|x|)), native exp/log only
__device__ __forceinline__ float softplus_(float x) {
    return fmaxf(x, 0.f) + __logf(1.f + __expf(-fabsf(x)));
}

// ================= mega prep kernel (block-range dispatch) =================
// [0,5248)      : fp32->fp16 convert x (1024 blk), in_proj (4096 blk), dt_w (128 blk)
// [5248,5504)   : W_emb [1024][256] -> W_embT fp16 [256][1024]
// [5504,5760)   : x_proj rows 0..79 -> fp16 padded to 128 rows
// [5760,6016)   : weff partials wp[c][d]
// [6016,7040)   : badd[n] = in_proj[n][:] . b_emb (fp32 read)
__global__ __launch_bounds__(256)
void prep_mega(const float* __restrict__ x, _Float16* __restrict__ xh,
               const float* __restrict__ ip, _Float16* __restrict__ iph,
               const float* __restrict__ dtw, _Float16* __restrict__ dtwh,
               const float* __restrict__ W_emb, _Float16* __restrict__ W_embT,
               const float* __restrict__ x_proj, _Float16* __restrict__ xp_h,
               const float* __restrict__ fc_w, const float* __restrict__ out_w,
               float* __restrict__ wp,
               const float* __restrict__ b_emb, float* __restrict__ badd) {
    __shared__ float tile[32][33];
    const int bid = blockIdx.x, tid = threadIdx.x;
    if (bid < 5248) {
        const float* in; _Float16* out; int i;
        if (bid < 1024)      { in = x;   out = xh;   i = bid * 256 + tid; }
        else if (bid < 5120) { in = ip;  out = iph;  i = (bid - 1024) * 256 + tid; }
        else                 { in = dtw; out = dtwh; i = (bid - 5120) * 256 + tid; }
        const float4 v = ((const float4*)in)[i];
        ((half4*)out)[i] = half4{(_Float16)v.x, (_Float16)v.y, (_Float16)v.z, (_Float16)v.w};
    } else if (bid < 5504) {
        const int bx = bid - 5248;
        const int m0 = (bx & 31) * 32, c0 = (bx >> 5) * 32;
        const int lc = tid & 31, lr = tid >> 5;
        #pragma unroll
        for (int ph = 0; ph < 4; ++ph)
            tile[lr + ph * 8][lc] = W_emb[(size_t)(m0 + lr + ph * 8) * INn + c0 + lc];
        __syncthreads();
        #pragma unroll
        for (int ph = 0; ph < 4; ++ph)
            W_embT[(size_t)(c0 + lr + ph * 8) * DMn + m0 + lc] = (_Float16)tile[lc][lr + ph * 8];
    } else if (bid < 5760) {
        const int i = (bid - 5504) * 256 + tid;
        const int r = i >> 9;
        const int c4 = i & 511;
        half4 h;
        if (r < XPW) {
            const float4 v = ((const float4*)(x_proj + (size_t)r * DIn))[c4];
            h = half4{(_Float16)v.x, (_Float16)v.y, (_Float16)v.z, (_Float16)v.w};
        } else {
            h = half4{(_Float16)0.f, (_Float16)0.f, (_Float16)0.f, (_Float16)0.f};
        }
        ((half4*)(xp_h + (size_t)r * DIn))[c4] = h;
    } else if (bid < 6016) {
        const int bx = bid - 5760;
        const int d = (bx & 7) * 256 + tid;
        const int c = bx >> 3;
        const int mstep = DMn / WCH; // 32
        float s = 0.f;
        for (int m = c * mstep; m < (c + 1) * mstep; ++m)
            s += fc_w[m] * out_w[(size_t)m * DIn + d];
        wp[(size_t)c * DIn + d] = s;
    } else {
        const int wave = tid >> 6, lane = tid & 63;
        const int n = (bid - 6016) * 4 + wave;
        const float4* row4 = (const float4*)(ip + (size_t)n * DMn);
        const float4* be4 = (const float4*)b_emb;
        float s = 0.f;
        #pragma unroll
        for (int q = 0; q < 4; ++q) {
            const float4 v = row4[lane + q * 64];
            const float4 bv = be4[lane + q * 64];
            s += v.x * bv.x + v.y * bv.y + v.z * bv.z + v.w * bv.w;
        }
        for (int off = 32; off > 0; off >>= 1) s += __shfl_down(s, off);
        if (lane == 0) badd[n] = s;
    }
}

// ---------------- generic split-K MFMA GEMM -> fp32 partials ----------------
__global__ __launch_bounds__(256)
void skgemm2(const _Float16* __restrict__ A, int lda,
             const _Float16* __restrict__ Bw, int ldb,
             float* __restrict__ P, int N, int Kc) {
    __shared__ _Float16 As[128 * 32];
    __shared__ _Float16 Bs[128 * 32];
    const int tid  = threadIdx.x;
    const int lane = tid & 63, wid = tid >> 6;
    const int wm = wid >> 1, wn = wid & 1;
    const int sk = blockIdx.x;
    const int m0 = blockIdx.y * 128;
    const int n0 = blockIdx.z * 128;
    const int M  = gridDim.y * 128;

    f32x4 acc[4][4] = {};
    const int kbeg = sk * Kc;
    for (int k0 = kbeg; k0 < kbeg + Kc; k0 += 32) {
        #pragma unroll
        for (int i = 0; i < 2; ++i) {
            const int off = tid * 16 + i * 4096;
            const int row = off >> 6;
            const int ch  = (off & 63) >> 1;
            const _Float16* ga = A  + (size_t)(m0 + row) * lda + k0 + ch;
            const _Float16* gb = Bw + (size_t)(n0 + row) * ldb + k0 + ch;
            __builtin_amdgcn_global_load_lds(
                (const __attribute__((address_space(1))) void*)ga,
                (__attribute__((address_space(3))) void*)(&As[off >> 1]), 16, 0, 0);
            __builtin_amdgcn_global_load_lds(
                (const __attribute__((address_space(1))) void*)gb,
                (__attribute__((address_space(3))) void*)(&Bs[off >> 1]), 16, 0, 0);
        }
        __syncthreads();
        const int ar = lane & 15;
        const int kq = (lane >> 4) * 8;
        half8 af[4], bf[4];
        #pragma unroll
        for (int i = 0; i < 4; ++i)
            af[i] = *(const half8*)&As[(wm * 64 + i * 16 + ar) * 32 + kq];
        #pragma unroll
        for (int j = 0; j < 4; ++j)
            bf[j] = *(const half8*)&Bs[(wn * 64 + j * 16 + ar) * 32 + kq];
        #pragma unroll
        for (int i = 0; i < 4; ++i)
            #pragma unroll
            for (int j = 0; j < 4; ++j)
                acc[i][j] = __builtin_amdgcn_mfma_f32_16x16x32_f16(af[i], bf[j], acc[i][j], 0, 0, 0);
        __syncthreads();
    }

    const int cr = (lane >> 4) * 4;
    const int cn = lane & 15;
    #pragma unroll
    for (int i = 0; i < 4; ++i) {
        #pragma unroll
        for (int j = 0; j < 4; ++j) {
            const int n = n0 + wn * 64 + j * 16 + cn;
            if (n < N) {
                #pragma unroll
                for (int r = 0; r < 4; ++r) {
                    const int m = m0 + wm * 64 + i * 16 + cr + r;
                    P[((size_t)sk * M + m) * N + n] = acc[i][j][r];
                }
            }
        }
    }
}

// sum split-K partials -> fp16
__global__ __launch_bounds__(256)
void skcomb(const float* __restrict__ P, _Float16* __restrict__ out, int total, int nsk) {
    const int i = blockIdx.x * 256 + threadIdx.x;
    if (i >= total) return;
    float s = 0.f;
    for (int k = 0; k < nsk; ++k) s += P[(size_t)k * total + i];
    out[i] = (_Float16)s;
}

// skcomb for dtB (blocks [0,1280)) + clast (blocks [1280,1296))
__global__ __launch_bounds__(256)
void skcombB_clast(const float* __restrict__ P, _Float16* __restrict__ dtBh,
                   const _Float16* __restrict__ u, const float* __restrict__ x_proj,
                   float* __restrict__ Clast) {
    const int bid = blockIdx.x, tid = threadIdx.x;
    if (bid < 1280) {
        const int i = bid * 256 + tid;   // over ML*XPW = 327680
        float s = 0.f;
        #pragma unroll
        for (int k = 0; k < 8; ++k) s += P[(size_t)k * (ML * XPW) + i];
        dtBh[i] = (_Float16)s;
    } else {
        const int wave = tid >> 6, lane = tid & 63;
        const int task = (bid - 1280) * 4 + wave;   // 64 tasks
        const int s_idx = task & 15, b = task >> 4;
        const _Float16* ur = u + ((size_t)b * Ln + (Ln - 1)) * DIn;
        const float* w = x_proj + (size_t)(XPW + s_idx) * DIn;
        float s = 0.f;
        for (int k = lane; k < DIn; k += 64) s += (float)ur[k] * w[k];
        for (int off = 32; off > 0; off >>= 1) s += __shfl_down(s, off);
        if (lane == 0) Clast[b * DSn + s_idx] = s;
    }
}

// ---------------- MFMA fp16 GEMM (128x128 tile, 4 waves, BK=32) ----------
template<int ACT, bool HAS_BIAS>
__global__ __launch_bounds__(256)
void hgemm(const _Float16* __restrict__ A, int lda,
           const _Float16* __restrict__ Bw, int ldb,
           const float* __restrict__ bias,
           _Float16* __restrict__ Ch, int ldc,
           int N, int K) {
    __shared__ _Float16 As[128 * 32];
    __shared__ _Float16 Bs[128 * 32];
    const int tid  = threadIdx.x;
    const int lane = tid & 63, wid = tid >> 6;
    const int wm = wid >> 1, wn = wid & 1;
    const int m0 = blockIdx.y * 128, n0 = blockIdx.x * 128;

    f32x4 acc[4][4] = {};

    for (int k0 = 0; k0 < K; k0 += 32) {
        #pragma unroll
        for (int i = 0; i < 2; ++i) {
            const int off = tid * 16 + i * 4096;
            const int row = off >> 6;
            const int ch  = (off & 63) >> 1;
            const _Float16* ga = A  + (size_t)(m0 + row) * lda + k0 + ch;
            const _Float16* gb = Bw + (size_t)(n0 + row) * ldb + k0 + ch;
            __builtin_amdgcn_global_load_lds(
                (const __attribute__((address_space(1))) void*)ga,
                (__attribute__((address_space(3))) void*)(&As[off >> 1]), 16, 0, 0);
            __builtin_amdgcn_global_load_lds(
                (const __attribute__((address_space(1))) void*)gb,
                (__attribute__((address_space(3))) void*)(&Bs[off >> 1]), 16, 0, 0);
        }
        __syncthreads();

        const int ar = lane & 15;
        const int kq = (lane >> 4) * 8;
        half8 af[4], bf[4];
        #pragma unroll
        for (int i = 0; i < 4; ++i)
            af[i] = *(const half8*)&As[(wm * 64 + i * 16 + ar) * 32 + kq];
        #pragma unroll
        for (int j = 0; j < 4; ++j)
            bf[j] = *(const half8*)&Bs[(wn * 64 + j * 16 + ar) * 32 + kq];
        #pragma unroll
        for (int i = 0; i < 4; ++i)
            #pragma unroll
            for (int j = 0; j < 4; ++j)
                acc[i][j] = __builtin_amdgcn_mfma_f32_16x16x32_f16(af[i], bf[j], acc[i][j], 0, 0, 0);
        __syncthreads();
    }

    const int cr = (lane >> 4) * 4;
    const int cn = lane & 15;
    #pragma unroll
    for (int i = 0; i < 4; ++i) {
        #pragma unroll
        for (int j = 0; j < 4; ++j) {
            const int n = n0 + wn * 64 + j * 16 + cn;
            if (n < N) {
                #pragma unroll
                for (int r = 0; r < 4; ++r) {
                    const int m = m0 + wm * 64 + i * 16 + cr + r;
                    float v = acc[i][j][r];
                    if (HAS_BIAS) v += bias[n];
                    if (ACT == 1) v = softplus_(v);
                    Ch[(size_t)m * ldc + n] = (_Float16)v;
                }
            }
        }
    }
}

// ---------------- z_last[b][j] = x[b,L-1,:].Wfold_z[j][:] + badd[DI+j] ----------------
__global__ __launch_bounds__(256)
void zlast_fold(const float* __restrict__ x, const _Float16* __restrict__ Wfh,
                const float* __restrict__ badd, float* __restrict__ zlast) {
    const int wave = threadIdx.x >> 6, lane = threadIdx.x & 63;
    const int j = blockIdx.x * 4 + wave;
    const int b = blockIdx.y;
    const float* xr = x + ((size_t)b * Ln + (Ln - 1)) * INn;
    const _Float16* w = Wfh + (size_t)(DIn + j) * INn;
    const half4 wv = *(const half4*)(w + lane * 4);
    const float4 xv = *(const float4*)(xr + lane * 4);
    float s = (float)wv[0] * xv.x + (float)wv[1] * xv.y + (float)wv[2] * xv.z + (float)wv[3] * xv.w;
    for (int off = 32; off > 0; off >>= 1) s += __shfl_down(s, off);
    if (lane == 0) zlast[(size_t)b * DIn + j] = s + badd[DIn + j];
}

// ---------------- conv+silu vectorized: 8 d (half8) x 4 t per thread ----------------
__global__ __launch_bounds__(256)
void conv_silu_v2(const _Float16* __restrict__ upre, const float* __restrict__ cw,
                  const float* __restrict__ cb, _Float16* __restrict__ uh) {
    const int tid = threadIdx.x;
    const int tg = blockIdx.x;
    const int b  = tg >> 8;
    const int t0 = (tg & 255) * 4;
    const int d0 = tid * 8;
    const size_t rowbase = ((size_t)b * Ln + t0) * DIn + d0;

    half8 hzero;
    #pragma unroll
    for (int q = 0; q < 8; ++q) hzero[q] = (_Float16)0.f;

    half8 rows[7];
    if (t0 >= 3) {
        #pragma unroll
        for (int r = 0; r < 7; ++r)
            rows[r] = *(const half8*)(upre + rowbase + (ptrdiff_t)(r - 3) * DIn);
    } else {
        #pragma unroll
        for (int r = 0; r < 7; ++r) {
            const int t = t0 - 3 + r;
            rows[r] = (t >= 0) ? *(const half8*)(upre + rowbase + (ptrdiff_t)(r - 3) * DIn) : hzero;
        }
    }

    f32x4 cwq[8];
    float cbv[8];
    #pragma unroll
    for (int q = 0; q < 8; ++q) {
        cwq[q] = *(const f32x4*)(cw + (size_t)(d0 + q) * DCn);
        cbv[q] = cb[d0 + q];
    }

    #pragma unroll
    for (int s = 0; s < 4; ++s) {
        half8 o;
        #pragma unroll
        for (int q = 0; q < 8; ++q) {
            float acc = cbv[q];
            #pragma unroll
            for (int j = 0; j < DCn; ++j) acc += (float)rows[s + j][q] * cwq[q][j];
            o[q] = (_Float16)silu_(acc);
        }
        *(half8*)(uh + rowbase + (size_t)s * DIn) = o;
    }
}

// ---------------- chunked scan ----------------
__global__ __launch_bounds__(256)
void scan_chunk_kernel(const _Float16* __restrict__ delta, const _Float16* __restrict__ u,
                       const _Float16* __restrict__ dtBh, const float* __restrict__ A_log,
                       float* __restrict__ cS, float* __restrict__ cH) {
    const int d = blockIdx.x * 256 + threadIdx.x;
    const int c = blockIdx.y, b = blockIdx.z;
    float A[DSn], h[DSn];
    const float4* al = (const float4*)(A_log + (size_t)d * DSn);
    #pragma unroll
    for (int q = 0; q < 4; ++q) {
        const float4 v = al[q];
        A[q * 4 + 0] = -__expf(v.x); A[q * 4 + 1] = -__expf(v.y);
        A[q * 4 + 2] = -__expf(v.z); A[q * 4 + 3] = -__expf(v.w);
        h[q * 4 + 0] = 0.f; h[q * 4 + 1] = 0.f; h[q * 4 + 2] = 0.f; h[q * 4 + 3] = 0.f;
    }
    float Ssum = 0.f;
    const size_t base = ((size_t)b * Ln + (size_t)c * CHUNK) * DIn + d;
    const _Float16* Bp = dtBh + ((size_t)b * Ln + (size_t)c * CHUNK) * XPW + DTRn;
    for (int tt = 0; tt < CHUNK; ++tt) {
        const float dl = (float)delta[base + (size_t)tt * DIn];
        const float uu = (float)u[base + (size_t)tt * DIn];
        const float du = dl * uu;
        Ssum += dl;
        const half8 bv0 = *(const half8*)(Bp + tt * XPW);
        const half8 bv1 = *(const half8*)(Bp + tt * XPW + 8);
        float Bv[DSn];
        #pragma unroll
        for (int q = 0; q < 8; ++q) { Bv[q] = (float)bv0[q]; Bv[8 + q] = (float)bv1[q]; }
        #pragma unroll
        for (int s = 0; s < DSn; ++s) h[s] = __expf(dl * A[s]) * h[s] + du * Bv[s];
    }
    const size_t cidx = ((size_t)b * NCHUNK + c) * DIn + d;
    cS[cidx] = Ssum;
    float4* outp = (float4*)(cH + cidx * DSn);
    outp[0] = float4{h[0], h[1], h[2], h[3]};
    outp[1] = float4{h[4], h[5], h[6], h[7]};
    outp[2] = float4{h[8], h[9], h[10], h[11]};
    outp[3] = float4{h[12], h[13], h[14], h[15]};
}

// ---------------- fold chunks + C-readout + D-skip + silu(z) gate ----------------
__global__ __launch_bounds__(256)
void combine_kernel(const float* __restrict__ cS, const float* __restrict__ cH,
                    const float* __restrict__ A_log, const float* __restrict__ Clast,
                    const float* __restrict__ Dp, const _Float16* __restrict__ u,
                    const float* __restrict__ zlast, float* __restrict__ ylast) {
    const int d = blockIdx.x * 256 + threadIdx.x;
    const int b = blockIdx.y;
    float A[DSn], h[DSn];
    const float4* al = (const float4*)(A_log + (size_t)d * DSn);
    #pragma unroll
    for (int q = 0; q < 4; ++q) {
        const float4 v = al[q];
        A[q * 4 + 0] = -__expf(v.x); A[q * 4 + 1] = -__expf(v.y);
        A[q * 4 + 2] = -__expf(v.z); A[q * 4 + 3] = -__expf(v.w);
        h[q * 4 + 0] = 0.f; h[q * 4 + 1] = 0.f; h[q * 4 + 2] = 0.f; h[q * 4 + 3] = 0.f;
    }
    for (int c = 0; c < NCHUNK; ++c) {
        const size_t cidx = ((size_t)b * NCHUNK + c) * DIn + d;
        const float Sc = cS[cidx];
        const float4* hp = (const float4*)(cH + cidx * DSn);
        const float4 h0 = hp[0], h1 = hp[1], h2 = hp[2], h3 = hp[3];
        const float hc[DSn] = {h0.x, h0.y, h0.z, h0.w, h1.x, h1.y, h1.z, h1.w,
                               h2.x, h2.y, h2.z, h2.w, h3.x, h3.y, h3.z, h3.w};
        #pragma unroll
        for (int s = 0; s < DSn; ++s) h[s] = __expf(A[s] * Sc) * h[s] + hc[s];
    }
    float y = 0.f;
    #pragma unroll
    for (int s = 0; s < DSn; ++s) y += h[s] * Clast[b * DSn + s];
    const float ul = (float)u[((size_t)b * Ln + (Ln - 1)) * DIn + d];
    y += Dp[d] * ul;
    const float z = zlast[(size_t)b * DIn + d];
    y *= silu_(z);
    ylast[(size_t)b * DIn + d] = y;
}

// ---------------- out[b] = fc_b + sum_d ylast[b][d] * sum_c wp[c][d] ----------------
__global__ __launch_bounds__(256)
void final_kernel(const float* __restrict__ ylast, const float* __restrict__ wp,
                  const float* __restrict__ fc_b, float* __restrict__ out) {
    const int b = blockIdx.x, tid = threadIdx.x;
    __shared__ float red[256];
    float s = 0.f;
    for (int d = tid; d < DIn; d += 256) {
        float w = 0.f;
        #pragma unroll
        for (int c = 0; c < WCH; ++c) w += wp[(size_t)c * DIn + d];
        s += ylast[(size_t)b * DIn + d] * w;
    }
    red[tid] = s;
    __syncthreads();
    for (int off = 128; off > 0; off >>= 1) {
        if (tid < off) red[tid] += red[tid + off];
        __syncthreads();
    }
    if (tid == 0) out[b] = red[0] + fc_b[0];
}

} // namespace

extern "C" void kernel_launch(void* const* d_in, const int* in_sizes, int n_in,
                              void* d_out, int out_size, void* d_ws, size_t ws_size,
                              hipStream_t stream) {
    (void)in_sizes; (void)n_in; (void)out_size; (void)ws_size;
    const float* x       = (const float*)d_in[0];
    const float* W_emb   = (const float*)d_in[1];
    const float* b_emb   = (const float*)d_in[2];
    const float* in_proj = (const float*)d_in[3];
    const float* conv_w  = (const float*)d_in[4];
    const float* conv_b  = (const float*)d_in[5];
    const float* x_proj  = (const float*)d_in[6];
    const float* dt_w    = (const float*)d_in[7];
    const float* dt_b    = (const float*)d_in[8];
    const float* A_log   = (const float*)d_in[9];
    const float* Dp      = (const float*)d_in[10];
    const float* out_w   = (const float*)d_in[11];
    const float* fc_w    = (const float*)d_in[12];
    const float* fc_b    = (const float*)d_in[13];
    float* out = (float*)d_out;
    char* w8 = (char*)d_ws;

    const size_t MB = 1ull << 20;
    _Float16* upreh    = (_Float16*)(w8);            // 16 MB [u_pre -> conv]
    _Float16* uh       = (_Float16*)(w8 + 16 * MB);  // 16 MB [conv -> scan/combine/clast]
    // region A (17 MB): wfold partials (16 MB, early) then deltah (16 MB, late)
    float*    wfoldP   = (float*)(w8 + 32 * MB);
    _Float16* deltah   = (_Float16*)(w8 + 32 * MB);
    // region B (10.5 MB): dtB split-K partials then cS/cH
    float*    skp      = (float*)(w8 + 49 * MB);
    float*    cS       = skp;
    float*    cH       = skp + (size_t)Bn * NCHUNK * DIn;
    _Float16* dtBh     = (_Float16*)(w8 + 60 * MB);  // 0.64 MB
    _Float16* xh       = (_Float16*)(w8 + 61 * MB);  // 2 MB
    _Float16* W_embT_h = (_Float16*)(w8 + 63 * MB);  // 0.5 MB  [256][1024]
    _Float16* in_projh = (_Float16*)(w8 + 64 * MB);  // 8 MB (full 4096 rows)
    _Float16* xp_h     = (_Float16*)(w8 + 72 * MB);  // 0.5 MB (padded 128 rows)
    _Float16* dt_wh    = (_Float16*)(w8 + 73 * MB);  // 0.25 MB
    _Float16* Wfoldh   = (_Float16*)(w8 + 74 * MB);  // 2 MB [4096][256]
    float*    wp       = (float*)(w8 + 76 * MB);     // 0.25 MB
    float*    badd     = (float*)(w8 + 77 * MB);     // 16 KB
    float*    zlast    = badd + 4096;
    float*    Clast    = zlast + (size_t)Bn * DIn;
    float*    ylast    = Clast + 256;

    // 0. all conversions + independent prep in one launch
    prep_mega<<<7040, 256, 0, stream>>>(x, xh, in_proj, in_projh, dt_w, dt_wh,
                                        W_emb, W_embT_h, x_proj, xp_h,
                                        fc_w, out_w, wp, b_emb, badd);

    // 1. WfoldFull = in_proj @ W_emb  [4096][256] (split-K 4 x Kc=256)
    skgemm2<<<dim3(4, ML / 128, 2), 256, 0, stream>>>(
        in_projh, DMn, W_embT_h, DMn, wfoldP, INn, 256);
    skcomb<<<(ML * INn + 255) / 256, 256, 0, stream>>>(wfoldP, Wfoldh, ML * INn, 4);

    // 2. upreh = fp16(x @ Wfold_u^T + badd_u)   K=256
    hgemm<0, true><<<dim3(DIn / 128, ML / 128), 256, 0, stream>>>(
        xh, INn, Wfoldh, INn, badd, upreh, DIn, DIn, INn);
    // 3. z_last from folded z-rows
    zlast_fold<<<dim3(DIn / 4, Bn), 256, 0, stream>>>(x, Wfoldh, badd, zlast);
    // 4. uh = fp16(silu(conv(upreh) + conv_b))
    conv_silu_v2<<<1024, 256, 0, stream>>>(upreh, conv_w, conv_b, uh);
    // 5. dtB = uh @ x_proj_w[0:80]^T (split-K 8 x Kc=256) -> fp16, + C_last
    skgemm2<<<dim3(8, ML / 128, 1), 256, 0, stream>>>(uh, DIn, xp_h, DIn, skp, XPW, 256);
    skcombB_clast<<<1296, 256, 0, stream>>>(skp, dtBh, uh, x_proj, Clast);
    // 7. deltah = fp16(softplus(dt @ dt_proj_w^T + dt_proj_b))  (region A: wfoldP dead)
    hgemm<1, true><<<dim3(DIn / 128, ML / 128), 256, 0, stream>>>(
        dtBh, XPW, dt_wh, DTRn, dt_b, deltah, DIn, DIn, DTRn);
    // 8. chunked scan (region B: skp dead)
    scan_chunk_kernel<<<dim3(DIn / 256, NCHUNK, Bn), 256, 0, stream>>>(
        deltah, uh, dtBh, A_log, cS, cH);
    // 9. combine + gate
    combine_kernel<<<dim3(DIn / 256, Bn), 256, 0, stream>>>(
        cS, cH, A_log, Clast, Dp, uh, zlast, ylast);
    // 10. out
    final_kernel<<<Bn, 256, 0, stream>>>(ylast, wp, fc_b, out);
}

// Round 6
// 135.904 us; speedup vs baseline: 4.1718x; 1.0982x over previous
//
#include <hip/hip_runtime.h>
#include <cstddef>
#include <cstdint>

namespace {

typedef _Float16 half8 __attribute__((ext_vector_type(8)));
typedef _Float16 half4 __attribute__((ext_vector_type(4)));
typedef float f32x4 __attribute__((ext_vector_type(4)));

constexpr int Bn   = 4;
constexpr int Ln   = 1024;
constexpr int INn  = 256;
constexpr int DMn  = 1024;
constexpr int DSn  = 16;
constexpr int DCn  = 4;
constexpr int DIn  = 2048;
constexpr int DTRn = 64;
constexpr int XPW  = DTRn + DSn;    // 80
constexpr int NCHUNK = 64;
constexpr int CHUNK  = Ln / NCHUNK; // 16
constexpr int WCH  = 32;            // weff m-chunks
constexpr int ML   = Bn * Ln;       // 4096

__device__ __forceinline__ float silu_(float x) { return x / (1.f + __expf(-x)); }
// stable fast softplus: max(x,0) + log(1+exp(-|x|)), native exp/log only
__device__ __forceinline__ float softplus_(float x) {
    return fmaxf(x, 0.f) + __logf(1.f + __expf(-fabsf(x)));
}

// ================= mega prep kernel (block-range dispatch) =================
__global__ __launch_bounds__(256)
void prep_mega(const float* __restrict__ x, _Float16* __restrict__ xh,
               const float* __restrict__ ip, _Float16* __restrict__ iph,
               const float* __restrict__ dtw, _Float16* __restrict__ dtwh,
               const float* __restrict__ W_emb, _Float16* __restrict__ W_embT,
               const float* __restrict__ x_proj, _Float16* __restrict__ xp_h,
               const float* __restrict__ fc_w, const float* __restrict__ out_w,
               float* __restrict__ wp,
               const float* __restrict__ b_emb, float* __restrict__ badd) {
    __shared__ float tile[32][33];
    const int bid = blockIdx.x, tid = threadIdx.x;
    if (bid < 5248) {
        const float* in; _Float16* out; int i;
        if (bid < 1024)      { in = x;   out = xh;   i = bid * 256 + tid; }
        else if (bid < 5120) { in = ip;  out = iph;  i = (bid - 1024) * 256 + tid; }
        else                 { in = dtw; out = dtwh; i = (bid - 5120) * 256 + tid; }
        const float4 v = ((const float4*)in)[i];
        ((half4*)out)[i] = half4{(_Float16)v.x, (_Float16)v.y, (_Float16)v.z, (_Float16)v.w};
    } else if (bid < 5504) {
        const int bx = bid - 5248;
        const int m0 = (bx & 31) * 32, c0 = (bx >> 5) * 32;
        const int lc = tid & 31, lr = tid >> 5;
        #pragma unroll
        for (int ph = 0; ph < 4; ++ph)
            tile[lr + ph * 8][lc] = W_emb[(size_t)(m0 + lr + ph * 8) * INn + c0 + lc];
        __syncthreads();
        #pragma unroll
        for (int ph = 0; ph < 4; ++ph)
            W_embT[(size_t)(c0 + lr + ph * 8) * DMn + m0 + lc] = (_Float16)tile[lc][lr + ph * 8];
    } else if (bid < 5760) {
        const int i = (bid - 5504) * 256 + tid;
        const int r = i >> 9;
        const int c4 = i & 511;
        half4 h;
        if (r < XPW) {
            const float4 v = ((const float4*)(x_proj + (size_t)r * DIn))[c4];
            h = half4{(_Float16)v.x, (_Float16)v.y, (_Float16)v.z, (_Float16)v.w};
        } else {
            h = half4{(_Float16)0.f, (_Float16)0.f, (_Float16)0.f, (_Float16)0.f};
        }
        ((half4*)(xp_h + (size_t)r * DIn))[c4] = h;
    } else if (bid < 6016) {
        const int bx = bid - 5760;
        const int d = (bx & 7) * 256 + tid;
        const int c = bx >> 3;
        const int mstep = DMn / WCH; // 32
        float s = 0.f;
        for (int m = c * mstep; m < (c + 1) * mstep; ++m)
            s += fc_w[m] * out_w[(size_t)m * DIn + d];
        wp[(size_t)c * DIn + d] = s;
    } else {
        const int wave = tid >> 6, lane = tid & 63;
        const int n = (bid - 6016) * 4 + wave;
        const float4* row4 = (const float4*)(ip + (size_t)n * DMn);
        const float4* be4 = (const float4*)b_emb;
        float s = 0.f;
        #pragma unroll
        for (int q = 0; q < 4; ++q) {
            const float4 v = row4[lane + q * 64];
            const float4 bv = be4[lane + q * 64];
            s += v.x * bv.x + v.y * bv.y + v.z * bv.z + v.w * bv.w;
        }
        for (int off = 32; off > 0; off >>= 1) s += __shfl_down(s, off);
        if (lane == 0) badd[n] = s;
    }
}

// ---------------- generic split-K MFMA GEMM -> fp32 partials ----------------
__global__ __launch_bounds__(256)
void skgemm2(const _Float16* __restrict__ A, int lda,
             const _Float16* __restrict__ Bw, int ldb,
             float* __restrict__ P, int N, int Kc) {
    __shared__ _Float16 As[128 * 32];
    __shared__ _Float16 Bs[128 * 32];
    const int tid  = threadIdx.x;
    const int lane = tid & 63, wid = tid >> 6;
    const int wm = wid >> 1, wn = wid & 1;
    const int sk = blockIdx.x;
    const int m0 = blockIdx.y * 128;
    const int n0 = blockIdx.z * 128;
    const int M  = gridDim.y * 128;

    f32x4 acc[4][4] = {};
    const int kbeg = sk * Kc;
    for (int k0 = kbeg; k0 < kbeg + Kc; k0 += 32) {
        #pragma unroll
        for (int i = 0; i < 2; ++i) {
            const int off = tid * 16 + i * 4096;
            const int row = off >> 6;
            const int ch  = (off & 63) >> 1;
            const _Float16* ga = A  + (size_t)(m0 + row) * lda + k0 + ch;
            const _Float16* gb = Bw + (size_t)(n0 + row) * ldb + k0 + ch;
            __builtin_amdgcn_global_load_lds(
                (const __attribute__((address_space(1))) void*)ga,
                (__attribute__((address_space(3))) void*)(&As[off >> 1]), 16, 0, 0);
            __builtin_amdgcn_global_load_lds(
                (const __attribute__((address_space(1))) void*)gb,
                (__attribute__((address_space(3))) void*)(&Bs[off >> 1]), 16, 0, 0);
        }
        __syncthreads();
        const int ar = lane & 15;
        const int kq = (lane >> 4) * 8;
        half8 af[4], bf[4];
        #pragma unroll
        for (int i = 0; i < 4; ++i)
            af[i] = *(const half8*)&As[(wm * 64 + i * 16 + ar) * 32 + kq];
        #pragma unroll
        for (int j = 0; j < 4; ++j)
            bf[j] = *(const half8*)&Bs[(wn * 64 + j * 16 + ar) * 32 + kq];
        #pragma unroll
        for (int i = 0; i < 4; ++i)
            #pragma unroll
            for (int j = 0; j < 4; ++j)
                acc[i][j] = __builtin_amdgcn_mfma_f32_16x16x32_f16(af[i], bf[j], acc[i][j], 0, 0, 0);
        __syncthreads();
    }

    const int cr = (lane >> 4) * 4;
    const int cn = lane & 15;
    #pragma unroll
    for (int i = 0; i < 4; ++i) {
        #pragma unroll
        for (int j = 0; j < 4; ++j) {
            const int n = n0 + wn * 64 + j * 16 + cn;
            if (n < N) {
                #pragma unroll
                for (int r = 0; r < 4; ++r) {
                    const int m = m0 + wm * 64 + i * 16 + cr + r;
                    P[((size_t)sk * M + m) * N + n] = acc[i][j][r];
                }
            }
        }
    }
}

// sum split-K partials -> fp16
__global__ __launch_bounds__(256)
void skcomb(const float* __restrict__ P, _Float16* __restrict__ out, int total, int nsk) {
    const int i = blockIdx.x * 256 + threadIdx.x;
    if (i >= total) return;
    float s = 0.f;
    for (int k = 0; k < nsk; ++k) s += P[(size_t)k * total + i];
    out[i] = (_Float16)s;
}

// skcomb for dtB (blocks [0,1280)) + clast (blocks [1280,1296))
__global__ __launch_bounds__(256)
void skcombB_clast(const float* __restrict__ P, _Float16* __restrict__ dtBh,
                   const _Float16* __restrict__ u, const float* __restrict__ x_proj,
                   float* __restrict__ Clast) {
    const int bid = blockIdx.x, tid = threadIdx.x;
    if (bid < 1280) {
        const int i = bid * 256 + tid;   // over ML*XPW = 327680
        float s = 0.f;
        #pragma unroll
        for (int k = 0; k < 8; ++k) s += P[(size_t)k * (ML * XPW) + i];
        dtBh[i] = (_Float16)s;
    } else {
        const int wave = tid >> 6, lane = tid & 63;
        const int task = (bid - 1280) * 4 + wave;   // 64 tasks
        const int s_idx = task & 15, b = task >> 4;
        const _Float16* ur = u + ((size_t)b * Ln + (Ln - 1)) * DIn;
        const float* w = x_proj + (size_t)(XPW + s_idx) * DIn;
        float s = 0.f;
        for (int k = lane; k < DIn; k += 64) s += (float)ur[k] * w[k];
        for (int off = 32; off > 0; off >>= 1) s += __shfl_down(s, off);
        if (lane == 0) Clast[b * DSn + s_idx] = s;
    }
}

// ---------------- MFMA fp16 GEMM (128x128 tile, 4 waves, BK=32) ----------
template<int ACT, bool HAS_BIAS>
__global__ __launch_bounds__(256)
void hgemm(const _Float16* __restrict__ A, int lda,
           const _Float16* __restrict__ Bw, int ldb,
           const float* __restrict__ bias,
           _Float16* __restrict__ Ch, int ldc,
           int N, int K) {
    __shared__ _Float16 As[128 * 32];
    __shared__ _Float16 Bs[128 * 32];
    const int tid  = threadIdx.x;
    const int lane = tid & 63, wid = tid >> 6;
    const int wm = wid >> 1, wn = wid & 1;
    const int m0 = blockIdx.y * 128, n0 = blockIdx.x * 128;

    f32x4 acc[4][4] = {};

    for (int k0 = 0; k0 < K; k0 += 32) {
        #pragma unroll
        for (int i = 0; i < 2; ++i) {
            const int off = tid * 16 + i * 4096;
            const int row = off >> 6;
            const int ch  = (off & 63) >> 1;
            const _Float16* ga = A  + (size_t)(m0 + row) * lda + k0 + ch;
            const _Float16* gb = Bw + (size_t)(n0 + row) * ldb + k0 + ch;
            __builtin_amdgcn_global_load_lds(
                (const __attribute__((address_space(1))) void*)ga,
                (__attribute__((address_space(3))) void*)(&As[off >> 1]), 16, 0, 0);
            __builtin_amdgcn_global_load_lds(
                (const __attribute__((address_space(1))) void*)gb,
                (__attribute__((address_space(3))) void*)(&Bs[off >> 1]), 16, 0, 0);
        }
        __syncthreads();

        const int ar = lane & 15;
        const int kq = (lane >> 4) * 8;
        half8 af[4], bf[4];
        #pragma unroll
        for (int i = 0; i < 4; ++i)
            af[i] = *(const half8*)&As[(wm * 64 + i * 16 + ar) * 32 + kq];
        #pragma unroll
        for (int j = 0; j < 4; ++j)
            bf[j] = *(const half8*)&Bs[(wn * 64 + j * 16 + ar) * 32 + kq];
        #pragma unroll
        for (int i = 0; i < 4; ++i)
            #pragma unroll
            for (int j = 0; j < 4; ++j)
                acc[i][j] = __builtin_amdgcn_mfma_f32_16x16x32_f16(af[i], bf[j], acc[i][j], 0, 0, 0);
        __syncthreads();
    }

    const int cr = (lane >> 4) * 4;
    const int cn = lane & 15;
    #pragma unroll
    for (int i = 0; i < 4; ++i) {
        #pragma unroll
        for (int j = 0; j < 4; ++j) {
            const int n = n0 + wn * 64 + j * 16 + cn;
            if (n < N) {
                #pragma unroll
                for (int r = 0; r < 4; ++r) {
                    const int m = m0 + wm * 64 + i * 16 + cr + r;
                    float v = acc[i][j][r];
                    if (HAS_BIAS) v += bias[n];
                    if (ACT == 1) v = softplus_(v);
                    Ch[(size_t)m * ldc + n] = (_Float16)v;
                }
            }
        }
    }
}

// ---------------- z_last[b][j] = x[b,L-1,:].Wfold_z[j][:] + badd[DI+j] ----------------
__global__ __launch_bounds__(256)
void zlast_fold(const float* __restrict__ x, const _Float16* __restrict__ Wfh,
                const float* __restrict__ badd, float* __restrict__ zlast) {
    const int wave = threadIdx.x >> 6, lane = threadIdx.x & 63;
    const int j = blockIdx.x * 4 + wave;
    const int b = blockIdx.y;
    const float* xr = x + ((size_t)b * Ln + (Ln - 1)) * INn;
    const _Float16* w = Wfh + (size_t)(DIn + j) * INn;
    const half4 wv = *(const half4*)(w + lane * 4);
    const float4 xv = *(const float4*)(xr + lane * 4);
    float s = (float)wv[0] * xv.x + (float)wv[1] * xv.y + (float)wv[2] * xv.z + (float)wv[3] * xv.w;
    for (int off = 32; off > 0; off >>= 1) s += __shfl_down(s, off);
    if (lane == 0) zlast[(size_t)b * DIn + j] = s + badd[DIn + j];
}

// ---------------- conv+silu vectorized: 8 d (half8) x 4 t per thread ----------------
__global__ __launch_bounds__(256)
void conv_silu_v2(const _Float16* __restrict__ upre, const float* __restrict__ cw,
                  const float* __restrict__ cb, _Float16* __restrict__ uh) {
    const int tid = threadIdx.x;
    const int tg = blockIdx.x;
    const int b  = tg >> 8;
    const int t0 = (tg & 255) * 4;
    const int d0 = tid * 8;
    const size_t rowbase = ((size_t)b * Ln + t0) * DIn + d0;

    half8 hzero;
    #pragma unroll
    for (int q = 0; q < 8; ++q) hzero[q] = (_Float16)0.f;

    half8 rows[7];
    if (t0 >= 3) {
        #pragma unroll
        for (int r = 0; r < 7; ++r)
            rows[r] = *(const half8*)(upre + rowbase + (ptrdiff_t)(r - 3) * DIn);
    } else {
        #pragma unroll
        for (int r = 0; r < 7; ++r) {
            const int t = t0 - 3 + r;
            rows[r] = (t >= 0) ? *(const half8*)(upre + rowbase + (ptrdiff_t)(r - 3) * DIn) : hzero;
        }
    }

    f32x4 cwq[8];
    float cbv[8];
    #pragma unroll
    for (int q = 0; q < 8; ++q) {
        cwq[q] = *(const f32x4*)(cw + (size_t)(d0 + q) * DCn);
        cbv[q] = cb[d0 + q];
    }

    #pragma unroll
    for (int s = 0; s < 4; ++s) {
        half8 o;
        #pragma unroll
        for (int q = 0; q < 8; ++q) {
            float acc = cbv[q];
            #pragma unroll
            for (int j = 0; j < DCn; ++j) acc += (float)rows[s + j][q] * cwq[q][j];
            o[q] = (_Float16)silu_(acc);
        }
        *(half8*)(uh + rowbase + (size_t)s * DIn) = o;
    }
}

// ---------------- chunked scan: per (b, c, d) run CHUNK=16 exact steps -------------
__global__ __launch_bounds__(256)
void scan_chunk_kernel(const _Float16* __restrict__ delta, const _Float16* __restrict__ u,
                       const _Float16* __restrict__ dtBh, const float* __restrict__ A_log,
                       float* __restrict__ cS, _Float16* __restrict__ cH) {
    const int d = blockIdx.x * 256 + threadIdx.x;
    const int c = blockIdx.y, b = blockIdx.z;
    float A[DSn], h[DSn];
    const float4* al = (const float4*)(A_log + (size_t)d * DSn);
    #pragma unroll
    for (int q = 0; q < 4; ++q) {
        const float4 v = al[q];
        A[q * 4 + 0] = -__expf(v.x); A[q * 4 + 1] = -__expf(v.y);
        A[q * 4 + 2] = -__expf(v.z); A[q * 4 + 3] = -__expf(v.w);
        h[q * 4 + 0] = 0.f; h[q * 4 + 1] = 0.f; h[q * 4 + 2] = 0.f; h[q * 4 + 3] = 0.f;
    }
    float Ssum = 0.f;
    const size_t base = ((size_t)b * Ln + (size_t)c * CHUNK) * DIn + d;
    const _Float16* Bp = dtBh + ((size_t)b * Ln + (size_t)c * CHUNK) * XPW + DTRn;
    #pragma unroll 4
    for (int tt = 0; tt < CHUNK; ++tt) {
        const float dl = (float)delta[base + (size_t)tt * DIn];
        const float uu = (float)u[base + (size_t)tt * DIn];
        const float du = dl * uu;
        Ssum += dl;
        const half8 bv0 = *(const half8*)(Bp + tt * XPW);
        const half8 bv1 = *(const half8*)(Bp + tt * XPW + 8);
        float Bv[DSn];
        #pragma unroll
        for (int q = 0; q < 8; ++q) { Bv[q] = (float)bv0[q]; Bv[8 + q] = (float)bv1[q]; }
        #pragma unroll
        for (int s = 0; s < DSn; ++s) h[s] = __expf(dl * A[s]) * h[s] + du * Bv[s];
    }
    const size_t cidx = ((size_t)b * NCHUNK + c) * DIn + d;
    cS[cidx] = Ssum;
    half8 o0, o1;
    #pragma unroll
    for (int q = 0; q < 8; ++q) { o0[q] = (_Float16)h[q]; o1[q] = (_Float16)h[8 + q]; }
    *(half8*)(cH + cidx * DSn) = o0;
    *(half8*)(cH + cidx * DSn + 8) = o1;
}

// ------- combine v2: thread = (d, s); fold 64 chunks; 16-lane reduce with C; gate ------
__global__ __launch_bounds__(256)
void combine_v2(const float* __restrict__ cS, const _Float16* __restrict__ cH,
                const float* __restrict__ A_log, const float* __restrict__ Clast,
                const float* __restrict__ Dp, const _Float16* __restrict__ u,
                const float* __restrict__ zlast, float* __restrict__ ylast) {
    const int tid = threadIdx.x;
    const int s = tid & 15;
    const int d = blockIdx.x * 16 + (tid >> 4);
    const int b = blockIdx.y;
    const float A = -__expf(A_log[(size_t)d * DSn + s]);
    float h = 0.f;
    const size_t cb0 = (size_t)b * NCHUNK;
    for (int c = 0; c < NCHUNK; ++c) {
        const size_t cidx = (cb0 + c) * DIn + d;
        h = __expf(A * cS[cidx]) * h + (float)cH[cidx * DSn + s];
    }
    float y = h * Clast[b * DSn + s];
    y += __shfl_xor(y, 1);
    y += __shfl_xor(y, 2);
    y += __shfl_xor(y, 4);
    y += __shfl_xor(y, 8);
    if (s == 0) {
        const float ul = (float)u[((size_t)b * Ln + (Ln - 1)) * DIn + d];
        float yy = y + Dp[d] * ul;
        yy *= silu_(zlast[(size_t)b * DIn + d]);
        ylast[(size_t)b * DIn + d] = yy;
    }
}

// ---------------- out[b] = fc_b + sum_d ylast[b][d] * sum_c wp[c][d] ----------------
__global__ __launch_bounds__(256)
void final_kernel(const float* __restrict__ ylast, const float* __restrict__ wp,
                  const float* __restrict__ fc_b, float* __restrict__ out) {
    const int b = blockIdx.x, tid = threadIdx.x;
    __shared__ float red[256];
    float s = 0.f;
    for (int d = tid; d < DIn; d += 256) {
        float w = 0.f;
        #pragma unroll
        for (int c = 0; c < WCH; ++c) w += wp[(size_t)c * DIn + d];
        s += ylast[(size_t)b * DIn + d] * w;
    }
    red[tid] = s;
    __syncthreads();
    for (int off = 128; off > 0; off >>= 1) {
        if (tid < off) red[tid] += red[tid + off];
        __syncthreads();
    }
    if (tid == 0) out[b] = red[0] + fc_b[0];
}

} // namespace

extern "C" void kernel_launch(void* const* d_in, const int* in_sizes, int n_in,
                              void* d_out, int out_size, void* d_ws, size_t ws_size,
                              hipStream_t stream) {
    (void)in_sizes; (void)n_in; (void)out_size; (void)ws_size;
    const float* x       = (const float*)d_in[0];
    const float* W_emb   = (const float*)d_in[1];
    const float* b_emb   = (const float*)d_in[2];
    const float* in_proj = (const float*)d_in[3];
    const float* conv_w  = (const float*)d_in[4];
    const float* conv_b  = (const float*)d_in[5];
    const float* x_proj  = (const float*)d_in[6];
    const float* dt_w    = (const float*)d_in[7];
    const float* dt_b    = (const float*)d_in[8];
    const float* A_log   = (const float*)d_in[9];
    const float* Dp      = (const float*)d_in[10];
    const float* out_w   = (const float*)d_in[11];
    const float* fc_w    = (const float*)d_in[12];
    const float* fc_b    = (const float*)d_in[13];
    float* out = (float*)d_out;
    char* w8 = (char*)d_ws;

    const size_t MB = 1ull << 20;
    _Float16* upreh    = (_Float16*)(w8);            // 16 MB [u_pre -> conv]
    _Float16* uh       = (_Float16*)(w8 + 16 * MB);  // 16 MB [conv -> scan/combine/clast]
    // region A (16 MB): wfold partials (early) then deltah (late)
    float*    wfoldP   = (float*)(w8 + 32 * MB);
    _Float16* deltah   = (_Float16*)(w8 + 32 * MB);
    // region B (19 MB): dtB split-K partials (10.5 MB) then cS (2 MB) + cH fp16 (16.8 MB)
    float*    skp      = (float*)(w8 + 48 * MB);
    float*    cS       = skp;
    _Float16* cH       = (_Float16*)(w8 + 50 * MB);
    _Float16* dtBh     = (_Float16*)(w8 + 67 * MB);  // 0.64 MB
    _Float16* xh       = (_Float16*)(w8 + 68 * MB);  // 2 MB
    _Float16* W_embT_h = (_Float16*)(w8 + 70 * MB);  // 0.5 MB  [256][1024]
    _Float16* in_projh = (_Float16*)(w8 + 71 * MB);  // 8 MB (full 4096 rows)
    _Float16* xp_h     = (_Float16*)(w8 + 79 * MB);  // 0.5 MB (padded 128 rows)
    _Float16* dt_wh    = (_Float16*)(w8 + 80 * MB);  // 0.25 MB
    _Float16* Wfoldh   = (_Float16*)(w8 + 81 * MB);  // 2 MB [4096][256]
    float*    wp       = (float*)(w8 + 83 * MB);     // 0.25 MB
    float*    badd     = (float*)(w8 + 84 * MB);     // 16 KB
    float*    zlast    = badd + 4096;
    float*    Clast    = zlast + (size_t)Bn * DIn;
    float*    ylast    = Clast + 256;

    // 0. all conversions + independent prep in one launch
    prep_mega<<<7040, 256, 0, stream>>>(x, xh, in_proj, in_projh, dt_w, dt_wh,
                                        W_emb, W_embT_h, x_proj, xp_h,
                                        fc_w, out_w, wp, b_emb, badd);

    // 1. WfoldFull = in_proj @ W_emb  [4096][256] (split-K 4 x Kc=256)
    skgemm2<<<dim3(4, ML / 128, 2), 256, 0, stream>>>(
        in_projh, DMn, W_embT_h, DMn, wfoldP, INn, 256);
    skcomb<<<(ML * INn + 255) / 256, 256, 0, stream>>>(wfoldP, Wfoldh, ML * INn, 4);

    // 2. upreh = fp16(x @ Wfold_u^T + badd_u)   K=256
    hgemm<0, true><<<dim3(DIn / 128, ML / 128), 256, 0, stream>>>(
        xh, INn, Wfoldh, INn, badd, upreh, DIn, DIn, INn);
    // 3. z_last from folded z-rows
    zlast_fold<<<dim3(DIn / 4, Bn), 256, 0, stream>>>(x, Wfoldh, badd, zlast);
    // 4. uh = fp16(silu(conv(upreh) + conv_b))
    conv_silu_v2<<<1024, 256, 0, stream>>>(upreh, conv_w, conv_b, uh);
    // 5. dtB = uh @ x_proj_w[0:80]^T (split-K 8 x Kc=256) -> fp16, + C_last
    skgemm2<<<dim3(8, ML / 128, 1), 256, 0, stream>>>(uh, DIn, xp_h, DIn, skp, XPW, 256);
    skcombB_clast<<<1296, 256, 0, stream>>>(skp, dtBh, uh, x_proj, Clast);
    // 7. deltah = fp16(softplus(dt @ dt_proj_w^T + dt_proj_b))  (region A: wfoldP dead)
    hgemm<1, true><<<dim3(DIn / 128, ML / 128), 256, 0, stream>>>(
        dtBh, XPW, dt_wh, DTRn, dt_b, deltah, DIn, DIn, DTRn);
    // 8. chunked scan, 64 chunks of 16 steps (region B: skp dead)
    scan_chunk_kernel<<<dim3(DIn / 256, NCHUNK, Bn), 256, 0, stream>>>(
        deltah, uh, dtBh, A_log, cS, cH);
    // 9. combine v2 ((d,s)-parallel) + gate
    combine_v2<<<dim3(DIn / 16, Bn), 256, 0, stream>>>(
        cS, cH, A_log, Clast, Dp, uh, zlast, ylast);
    // 10. out
    final_kernel<<<Bn, 256, 0, stream>>>(ylast, wp, fc_b, out);
}

// Round 7
// 127.383 us; speedup vs baseline: 4.4509x; 1.0669x over previous
//
#include <hip/hip_runtime.h>
#include <cstddef>
#include <cstdint>

namespace {

typedef _Float16 half8 __attribute__((ext_vector_type(8)));
typedef _Float16 half4 __attribute__((ext_vector_type(4)));
typedef float f32x4 __attribute__((ext_vector_type(4)));

constexpr int Bn   = 4;
constexpr int Ln   = 1024;
constexpr int INn  = 256;
constexpr int DMn  = 1024;
constexpr int DSn  = 16;
constexpr int DCn  = 4;
constexpr int DIn  = 2048;
constexpr int DTRn = 64;
constexpr int XPW  = DTRn + DSn;    // 80
constexpr int NCHUNK = 64;
constexpr int CHUNK  = Ln / NCHUNK; // 16
constexpr int WCH  = 32;            // weff m-chunks
constexpr int ML   = Bn * Ln;       // 4096

__device__ __forceinline__ float silu_(float x) { return x / (1.f + __expf(-x)); }
__device__ __forceinline__ float softplus_(float x) {
    return fmaxf(x, 0.f) + __logf(1.f + __expf(-fabsf(x)));
}

// ================= mega prep kernel (block-range dispatch) =================
// [0,4096)      : in_proj row fp32->fp16 convert + badd[n] = in_proj[n].b_emb
// [4096,5120)   : x f2h
// [5120,5248)   : dt_w f2h
// [5248,5504)   : W_emb -> W_embT fp16
// [5504,5760)   : x_proj rows 0..79 -> fp16 padded to 128 rows
// [5760,6016)   : weff partials wp[c][d]
// 6016          : out[b] = fc_b (re-init each call for the fused-atomic finale)
__global__ __launch_bounds__(256)
void prep_mega(const float* __restrict__ x, _Float16* __restrict__ xh,
               const float* __restrict__ ip, _Float16* __restrict__ iph,
               const float* __restrict__ dtw, _Float16* __restrict__ dtwh,
               const float* __restrict__ W_emb, _Float16* __restrict__ W_embT,
               const float* __restrict__ x_proj, _Float16* __restrict__ xp_h,
               const float* __restrict__ fc_w, const float* __restrict__ out_w,
               float* __restrict__ wp,
               const float* __restrict__ b_emb, float* __restrict__ badd,
               const float* __restrict__ fc_b, float* __restrict__ out) {
    __shared__ float tile[32][33];
    const int bid = blockIdx.x, tid = threadIdx.x;
    if (bid < 4096) {
        const int n = bid;
        const float4 v = ((const float4*)ip)[n * 256 + tid];
        ((half4*)iph)[n * 256 + tid] =
            half4{(_Float16)v.x, (_Float16)v.y, (_Float16)v.z, (_Float16)v.w};
        const float4 bv = ((const float4*)b_emb)[tid];
        float s = v.x * bv.x + v.y * bv.y + v.z * bv.z + v.w * bv.w;
        for (int off = 32; off > 0; off >>= 1) s += __shfl_down(s, off);
        if ((tid & 63) == 0) tile[0][tid >> 6] = s;
        __syncthreads();
        if (tid == 0) badd[n] = tile[0][0] + tile[0][1] + tile[0][2] + tile[0][3];
    } else if (bid < 5248) {
        const float* in; _Float16* outp; int i;
        if (bid < 5120) { in = x;   outp = xh;   i = (bid - 4096) * 256 + tid; }
        else            { in = dtw; outp = dtwh; i = (bid - 5120) * 256 + tid; }
        const float4 v = ((const float4*)in)[i];
        ((half4*)outp)[i] = half4{(_Float16)v.x, (_Float16)v.y, (_Float16)v.z, (_Float16)v.w};
    } else if (bid < 5504) {
        const int bx = bid - 5248;
        const int m0 = (bx & 31) * 32, c0 = (bx >> 5) * 32;
        const int lc = tid & 31, lr = tid >> 5;
        #pragma unroll
        for (int ph = 0; ph < 4; ++ph)
            tile[lr + ph * 8][lc] = W_emb[(size_t)(m0 + lr + ph * 8) * INn + c0 + lc];
        __syncthreads();
        #pragma unroll
        for (int ph = 0; ph < 4; ++ph)
            W_embT[(size_t)(c0 + lr + ph * 8) * DMn + m0 + lc] = (_Float16)tile[lc][lr + ph * 8];
    } else if (bid < 5760) {
        const int i = (bid - 5504) * 256 + tid;
        const int r = i >> 9;
        const int c4 = i & 511;
        half4 h;
        if (r < XPW) {
            const float4 v = ((const float4*)(x_proj + (size_t)r * DIn))[c4];
            h = half4{(_Float16)v.x, (_Float16)v.y, (_Float16)v.z, (_Float16)v.w};
        } else {
            h = half4{(_Float16)0.f, (_Float16)0.f, (_Float16)0.f, (_Float16)0.f};
        }
        ((half4*)(xp_h + (size_t)r * DIn))[c4] = h;
    } else if (bid < 6016) {
        const int bx = bid - 5760;
        const int d = (bx & 7) * 256 + tid;
        const int c = bx >> 3;
        const int mstep = DMn / WCH; // 32
        float s = 0.f;
        for (int m = c * mstep; m < (c + 1) * mstep; ++m)
            s += fc_w[m] * out_w[(size_t)m * DIn + d];
        wp[(size_t)c * DIn + d] = s;
    } else {
        if (tid < Bn) out[tid] = fc_b[0];
    }
}

// ---------------- generic split-K MFMA GEMM -> fp32 partials ----------------
__global__ __launch_bounds__(256)
void skgemm2(const _Float16* __restrict__ A, int lda,
             const _Float16* __restrict__ Bw, int ldb,
             float* __restrict__ P, int N, int Kc) {
    __shared__ _Float16 As[128 * 32];
    __shared__ _Float16 Bs[128 * 32];
    const int tid  = threadIdx.x;
    const int lane = tid & 63, wid = tid >> 6;
    const int wm = wid >> 1, wn = wid & 1;
    const int sk = blockIdx.x;
    const int m0 = blockIdx.y * 128;
    const int n0 = blockIdx.z * 128;
    const int M  = gridDim.y * 128;

    f32x4 acc[4][4] = {};
    const int kbeg = sk * Kc;
    for (int k0 = kbeg; k0 < kbeg + Kc; k0 += 32) {
        #pragma unroll
        for (int i = 0; i < 2; ++i) {
            const int off = tid * 16 + i * 4096;
            const int row = off >> 6;
            const int ch  = (off & 63) >> 1;
            const _Float16* ga = A  + (size_t)(m0 + row) * lda + k0 + ch;
            const _Float16* gb = Bw + (size_t)(n0 + row) * ldb + k0 + ch;
            __builtin_amdgcn_global_load_lds(
                (const __attribute__((address_space(1))) void*)ga,
                (__attribute__((address_space(3))) void*)(&As[off >> 1]), 16, 0, 0);
            __builtin_amdgcn_global_load_lds(
                (const __attribute__((address_space(1))) void*)gb,
                (__attribute__((address_space(3))) void*)(&Bs[off >> 1]), 16, 0, 0);
        }
        __syncthreads();
        const int ar = lane & 15;
        const int kq = (lane >> 4) * 8;
        half8 af[4], bf[4];
        #pragma unroll
        for (int i = 0; i < 4; ++i)
            af[i] = *(const half8*)&As[(wm * 64 + i * 16 + ar) * 32 + kq];
        #pragma unroll
        for (int j = 0; j < 4; ++j)
            bf[j] = *(const half8*)&Bs[(wn * 64 + j * 16 + ar) * 32 + kq];
        #pragma unroll
        for (int i = 0; i < 4; ++i)
            #pragma unroll
            for (int j = 0; j < 4; ++j)
                acc[i][j] = __builtin_amdgcn_mfma_f32_16x16x32_f16(af[i], bf[j], acc[i][j], 0, 0, 0);
        __syncthreads();
    }

    const int cr = (lane >> 4) * 4;
    const int cn = lane & 15;
    #pragma unroll
    for (int i = 0; i < 4; ++i) {
        #pragma unroll
        for (int j = 0; j < 4; ++j) {
            const int n = n0 + wn * 64 + j * 16 + cn;
            if (n < N) {
                #pragma unroll
                for (int r = 0; r < 4; ++r) {
                    const int m = m0 + wm * 64 + i * 16 + cr + r;
                    P[((size_t)sk * M + m) * N + n] = acc[i][j][r];
                }
            }
        }
    }
}

// sum split-K partials -> fp16
__global__ __launch_bounds__(256)
void skcomb(const float* __restrict__ P, _Float16* __restrict__ out, int total, int nsk) {
    const int i = blockIdx.x * 256 + threadIdx.x;
    if (i >= total) return;
    float s = 0.f;
    for (int k = 0; k < nsk; ++k) s += P[(size_t)k * total + i];
    out[i] = (_Float16)s;
}

// skcomb for dtB (blocks [0,1280)) + clast (blocks [1280,1296))
__global__ __launch_bounds__(256)
void skcombB_clast(const float* __restrict__ P, _Float16* __restrict__ dtBh,
                   const _Float16* __restrict__ u, const float* __restrict__ x_proj,
                   float* __restrict__ Clast) {
    const int bid = blockIdx.x, tid = threadIdx.x;
    if (bid < 1280) {
        const int i = bid * 256 + tid;   // over ML*XPW = 327680
        float s = 0.f;
        #pragma unroll
        for (int k = 0; k < 8; ++k) s += P[(size_t)k * (ML * XPW) + i];
        dtBh[i] = (_Float16)s;
    } else {
        const int wave = tid >> 6, lane = tid & 63;
        const int task = (bid - 1280) * 4 + wave;   // 64 tasks
        const int s_idx = task & 15, b = task >> 4;
        const _Float16* ur = u + ((size_t)b * Ln + (Ln - 1)) * DIn;
        const float* w = x_proj + (size_t)(XPW + s_idx) * DIn;
        float s = 0.f;
        for (int k = lane; k < DIn; k += 64) s += (float)ur[k] * w[k];
        for (int off = 32; off > 0; off >>= 1) s += __shfl_down(s, off);
        if (lane == 0) Clast[b * DSn + s_idx] = s;
    }
}

// ---------------- MFMA fp16 GEMM (128x128 tile, 4 waves, BK=32) ----------
template<int ACT, bool HAS_BIAS>
__global__ __launch_bounds__(256)
void hgemm(const _Float16* __restrict__ A, int lda,
           const _Float16* __restrict__ Bw, int ldb,
           const float* __restrict__ bias,
           _Float16* __restrict__ Ch, int ldc,
           int N, int K) {
    __shared__ _Float16 As[128 * 32];
    __shared__ _Float16 Bs[128 * 32];
    const int tid  = threadIdx.x;
    const int lane = tid & 63, wid = tid >> 6;
    const int wm = wid >> 1, wn = wid & 1;
    const int m0 = blockIdx.y * 128, n0 = blockIdx.x * 128;

    f32x4 acc[4][4] = {};

    for (int k0 = 0; k0 < K; k0 += 32) {
        #pragma unroll
        for (int i = 0; i < 2; ++i) {
            const int off = tid * 16 + i * 4096;
            const int row = off >> 6;
            const int ch  = (off & 63) >> 1;
            const _Float16* ga = A  + (size_t)(m0 + row) * lda + k0 + ch;
            const _Float16* gb = Bw + (size_t)(n0 + row) * ldb + k0 + ch;
            __builtin_amdgcn_global_load_lds(
                (const __attribute__((address_space(1))) void*)ga,
                (__attribute__((address_space(3))) void*)(&As[off >> 1]), 16, 0, 0);
            __builtin_amdgcn_global_load_lds(
                (const __attribute__((address_space(1))) void*)gb,
                (__attribute__((address_space(3))) void*)(&Bs[off >> 1]), 16, 0, 0);
        }
        __syncthreads();

        const int ar = lane & 15;
        const int kq = (lane >> 4) * 8;
        half8 af[4], bf[4];
        #pragma unroll
        for (int i = 0; i < 4; ++i)
            af[i] = *(const half8*)&As[(wm * 64 + i * 16 + ar) * 32 + kq];
        #pragma unroll
        for (int j = 0; j < 4; ++j)
            bf[j] = *(const half8*)&Bs[(wn * 64 + j * 16 + ar) * 32 + kq];
        #pragma unroll
        for (int i = 0; i < 4; ++i)
            #pragma unroll
            for (int j = 0; j < 4; ++j)
                acc[i][j] = __builtin_amdgcn_mfma_f32_16x16x32_f16(af[i], bf[j], acc[i][j], 0, 0, 0);
        __syncthreads();
    }

    const int cr = (lane >> 4) * 4;
    const int cn = lane & 15;
    #pragma unroll
    for (int i = 0; i < 4; ++i) {
        #pragma unroll
        for (int j = 0; j < 4; ++j) {
            const int n = n0 + wn * 64 + j * 16 + cn;
            if (n < N) {
                #pragma unroll
                for (int r = 0; r < 4; ++r) {
                    const int m = m0 + wm * 64 + i * 16 + cr + r;
                    float v = acc[i][j][r];
                    if (HAS_BIAS) v += bias[n];
                    if (ACT == 1) v = softplus_(v);
                    Ch[(size_t)m * ldc + n] = (_Float16)v;
                }
            }
        }
    }
}

// ------- conv+silu (blocks [0,1024)) + z_last fold GEMV (blocks [1024,1056)) -------
__global__ __launch_bounds__(256)
void conv_zlast(const _Float16* __restrict__ upre, const float* __restrict__ cw,
                const float* __restrict__ cb, _Float16* __restrict__ uh,
                const float* __restrict__ x, const _Float16* __restrict__ Wfh,
                const float* __restrict__ badd, float* __restrict__ zlast) {
    const int tid = threadIdx.x;
    const int bid = blockIdx.x;
    if (bid < 1024) {
        const int b  = bid >> 8;
        const int t0 = (bid & 255) * 4;
        const int d0 = tid * 8;
        const size_t rowbase = ((size_t)b * Ln + t0) * DIn + d0;

        half8 hzero;
        #pragma unroll
        for (int q = 0; q < 8; ++q) hzero[q] = (_Float16)0.f;

        half8 rows[7];
        if (t0 >= 3) {
            #pragma unroll
            for (int r = 0; r < 7; ++r)
                rows[r] = *(const half8*)(upre + rowbase + (ptrdiff_t)(r - 3) * DIn);
        } else {
            #pragma unroll
            for (int r = 0; r < 7; ++r) {
                const int t = t0 - 3 + r;
                rows[r] = (t >= 0) ? *(const half8*)(upre + rowbase + (ptrdiff_t)(r - 3) * DIn) : hzero;
            }
        }

        f32x4 cwq[8];
        float cbv[8];
        #pragma unroll
        for (int q = 0; q < 8; ++q) {
            cwq[q] = *(const f32x4*)(cw + (size_t)(d0 + q) * DCn);
            cbv[q] = cb[d0 + q];
        }

        #pragma unroll
        for (int s = 0; s < 4; ++s) {
            half8 o;
            #pragma unroll
            for (int q = 0; q < 8; ++q) {
                float acc = cbv[q];
                #pragma unroll
                for (int j = 0; j < DCn; ++j) acc += (float)rows[s + j][q] * cwq[q][j];
                o[q] = (_Float16)silu_(acc);
            }
            *(half8*)(uh + rowbase + (size_t)s * DIn) = o;
        }
    } else {
        const int task = (bid - 1024) * 256 + tid;    // 8192 = 2048 j x 4 b
        const int j = task & (DIn - 1), b = task >> 11;
        const float4* x4 = (const float4*)(x + ((size_t)b * Ln + (Ln - 1)) * INn);
        const half4* w4 = (const half4*)(Wfh + (size_t)(DIn + j) * INn);
        float s = 0.f;
        #pragma unroll 8
        for (int q = 0; q < 64; ++q) {
            const float4 xv = x4[q];
            const half4 wv = w4[q];
            s += (float)wv[0] * xv.x + (float)wv[1] * xv.y
               + (float)wv[2] * xv.z + (float)wv[3] * xv.w;
        }
        zlast[(size_t)b * DIn + j] = s + badd[DIn + j];
    }
}

// ---------------- chunked scan: per (b, c, d) run CHUNK=16 exact steps -------------
// Uses the A[s] = (s+1)*A[0] structure (runtime-checked) to replace 16 exps/step
// with 1 exp + a squaring tree.
__global__ __launch_bounds__(256)
void scan_chunk_kernel(const _Float16* __restrict__ delta, const _Float16* __restrict__ u,
                       const _Float16* __restrict__ dtBh, const float* __restrict__ A_log,
                       float* __restrict__ cS, _Float16* __restrict__ cH) {
    const int d = blockIdx.x * 256 + threadIdx.x;
    const int c = blockIdx.y, b = blockIdx.z;
    float A[DSn], h[DSn];
    const float4* al = (const float4*)(A_log + (size_t)d * DSn);
    #pragma unroll
    for (int q = 0; q < 4; ++q) {
        const float4 v = al[q];
        A[q * 4 + 0] = -__expf(v.x); A[q * 4 + 1] = -__expf(v.y);
        A[q * 4 + 2] = -__expf(v.z); A[q * 4 + 3] = -__expf(v.w);
        h[q * 4 + 0] = 0.f; h[q * 4 + 1] = 0.f; h[q * 4 + 2] = 0.f; h[q * 4 + 3] = 0.f;
    }
    const float A0 = A[0];
    bool structured = true;
    #pragma unroll
    for (int s = 1; s < DSn; ++s)
        structured = structured && (fabsf(A[s] - (float)(s + 1) * A0) <= 1e-4f * (s + 1));

    float Ssum = 0.f;
    const size_t base = ((size_t)b * Ln + (size_t)c * CHUNK) * DIn + d;
    const _Float16* Bp = dtBh + ((size_t)b * Ln + (size_t)c * CHUNK) * XPW + DTRn;
    if (structured) {
        #pragma unroll 4
        for (int tt = 0; tt < CHUNK; ++tt) {
            const float dl = (float)delta[base + (size_t)tt * DIn];
            const float uu = (float)u[base + (size_t)tt * DIn];
            const float du = dl * uu;
            Ssum += dl;
            const half8 bv0 = *(const half8*)(Bp + tt * XPW);
            const half8 bv1 = *(const half8*)(Bp + tt * XPW + 8);
            float Bv[DSn];
            #pragma unroll
            for (int q = 0; q < 8; ++q) { Bv[q] = (float)bv0[q]; Bv[8 + q] = (float)bv1[q]; }
            const float e1 = __expf(dl * A0);
            const float e2 = e1 * e1, e4 = e2 * e2, e8 = e4 * e4;
            float E[DSn];
            E[0] = e1;      E[1] = e2;      E[2] = e2 * e1;  E[3] = e4;
            E[4] = e4 * e1; E[5] = e4 * e2; E[6] = E[5] * e1; E[7] = e8;
            E[8] = e8 * e1; E[9] = e8 * e2; E[10] = E[9] * e1; E[11] = e8 * e4;
            E[12] = E[11] * e1; E[13] = E[11] * e2; E[14] = E[13] * e1; E[15] = e8 * e8;
            #pragma unroll
            for (int s = 0; s < DSn; ++s) h[s] = E[s] * h[s] + du * Bv[s];
        }
    } else {
        #pragma unroll 4
        for (int tt = 0; tt < CHUNK; ++tt) {
            const float dl = (float)delta[base + (size_t)tt * DIn];
            const float uu = (float)u[base + (size_t)tt * DIn];
            const float du = dl * uu;
            Ssum += dl;
            const half8 bv0 = *(const half8*)(Bp + tt * XPW);
            const half8 bv1 = *(const half8*)(Bp + tt * XPW + 8);
            float Bv[DSn];
            #pragma unroll
            for (int q = 0; q < 8; ++q) { Bv[q] = (float)bv0[q]; Bv[8 + q] = (float)bv1[q]; }
            #pragma unroll
            for (int s = 0; s < DSn; ++s) h[s] = __expf(dl * A[s]) * h[s] + du * Bv[s];
        }
    }
    const size_t cidx = ((size_t)b * NCHUNK + c) * DIn + d;
    cS[cidx] = Ssum;
    half8 o0, o1;
    #pragma unroll
    for (int q = 0; q < 8; ++q) { o0[q] = (_Float16)h[q]; o1[q] = (_Float16)h[8 + q]; }
    *(half8*)(cH + cidx * DSn) = o0;
    *(half8*)(cH + cidx * DSn + 8) = o1;
}

// ------- combine v3: thread = (d, s); fold chunks; reduce; gate; atomic out -------
__global__ __launch_bounds__(256)
void combine_v3(const float* __restrict__ cS, const _Float16* __restrict__ cH,
                const float* __restrict__ A_log, const float* __restrict__ Clast,
                const float* __restrict__ Dp, const _Float16* __restrict__ u,
                const float* __restrict__ zlast, const float* __restrict__ wp,
                float* __restrict__ out) {
    __shared__ float acc[16];
    const int tid = threadIdx.x;
    const int s = tid & 15;
    const int d = blockIdx.x * 16 + (tid >> 4);
    const int b = blockIdx.y;
    const float A = -__expf(A_log[(size_t)d * DSn + s]);
    float h = 0.f;
    const size_t cb0 = (size_t)b * NCHUNK;
    for (int c = 0; c < NCHUNK; ++c) {
        const size_t cidx = (cb0 + c) * DIn + d;
        h = __expf(A * cS[cidx]) * h + (float)cH[cidx * DSn + s];
    }
    float y = h * Clast[b * DSn + s];
    y += __shfl_xor(y, 1);
    y += __shfl_xor(y, 2);
    y += __shfl_xor(y, 4);
    y += __shfl_xor(y, 8);
    if (s == 0) {
        const float ul = (float)u[((size_t)b * Ln + (Ln - 1)) * DIn + d];
        float yy = y + Dp[d] * ul;
        yy *= silu_(zlast[(size_t)b * DIn + d]);
        float w = 0.f;
        #pragma unroll
        for (int c = 0; c < WCH; ++c) w += wp[(size_t)c * DIn + d];
        acc[tid >> 4] = yy * w;
    }
    __syncthreads();
    if (tid == 0) {
        float t = 0.f;
        #pragma unroll
        for (int i = 0; i < 16; ++i) t += acc[i];
        atomicAdd(&out[b], t);
    }
}

} // namespace

extern "C" void kernel_launch(void* const* d_in, const int* in_sizes, int n_in,
                              void* d_out, int out_size, void* d_ws, size_t ws_size,
                              hipStream_t stream) {
    (void)in_sizes; (void)n_in; (void)out_size; (void)ws_size;
    const float* x       = (const float*)d_in[0];
    const float* W_emb   = (const float*)d_in[1];
    const float* b_emb   = (const float*)d_in[2];
    const float* in_proj = (const float*)d_in[3];
    const float* conv_w  = (const float*)d_in[4];
    const float* conv_b  = (const float*)d_in[5];
    const float* x_proj  = (const float*)d_in[6];
    const float* dt_w    = (const float*)d_in[7];
    const float* dt_b    = (const float*)d_in[8];
    const float* A_log   = (const float*)d_in[9];
    const float* Dp      = (const float*)d_in[10];
    const float* out_w   = (const float*)d_in[11];
    const float* fc_w    = (const float*)d_in[12];
    const float* fc_b    = (const float*)d_in[13];
    float* out = (float*)d_out;
    char* w8 = (char*)d_ws;

    const size_t MB = 1ull << 20;
    _Float16* upreh    = (_Float16*)(w8);            // 16 MB [u_pre -> conv]
    _Float16* uh       = (_Float16*)(w8 + 16 * MB);  // 16 MB [conv -> scan/combine/clast]
    // region A (16 MB): wfold partials (early) then deltah (late)
    float*    wfoldP   = (float*)(w8 + 32 * MB);
    _Float16* deltah   = (_Float16*)(w8 + 32 * MB);
    // region B (19 MB): dtB split-K partials (10.5 MB) then cS (2 MB) + cH fp16 (16.8 MB)
    float*    skp      = (float*)(w8 + 48 * MB);
    float*    cS       = skp;
    _Float16* cH       = (_Float16*)(w8 + 50 * MB);
    _Float16* dtBh     = (_Float16*)(w8 + 67 * MB);  // 0.64 MB
    _Float16* xh       = (_Float16*)(w8 + 68 * MB);  // 2 MB
    _Float16* W_embT_h = (_Float16*)(w8 + 70 * MB);  // 0.5 MB  [256][1024]
    _Float16* in_projh = (_Float16*)(w8 + 71 * MB);  // 8 MB (full 4096 rows)
    _Float16* xp_h     = (_Float16*)(w8 + 79 * MB);  // 0.5 MB (padded 128 rows)
    _Float16* dt_wh    = (_Float16*)(w8 + 80 * MB);  // 0.25 MB
    _Float16* Wfoldh   = (_Float16*)(w8 + 81 * MB);  // 2 MB [4096][256]
    float*    wp       = (float*)(w8 + 83 * MB);     // 0.25 MB
    float*    badd     = (float*)(w8 + 84 * MB);     // 16 KB
    float*    zlast    = badd + 4096;
    float*    Clast    = zlast + (size_t)Bn * DIn;

    // 0. all conversions + independent prep + out init (one launch)
    prep_mega<<<6017, 256, 0, stream>>>(x, xh, in_proj, in_projh, dt_w, dt_wh,
                                        W_emb, W_embT_h, x_proj, xp_h,
                                        fc_w, out_w, wp, b_emb, badd, fc_b, out);

    // 1. WfoldFull = in_proj @ W_emb  [4096][256] (split-K 4 x Kc=256)
    skgemm2<<<dim3(4, ML / 128, 2), 256, 0, stream>>>(
        in_projh, DMn, W_embT_h, DMn, wfoldP, INn, 256);
    skcomb<<<(ML * INn + 255) / 256, 256, 0, stream>>>(wfoldP, Wfoldh, ML * INn, 4);

    // 2. upreh = fp16(x @ Wfold_u^T + badd_u)   K=256
    hgemm<0, true><<<dim3(DIn / 128, ML / 128), 256, 0, stream>>>(
        xh, INn, Wfoldh, INn, badd, upreh, DIn, DIn, INn);
    // 3. uh = fp16(silu(conv(upreh) + conv_b));  + z_last fold GEMV
    conv_zlast<<<1056, 256, 0, stream>>>(upreh, conv_w, conv_b, uh, x, Wfoldh, badd, zlast);
    // 4. dtB = uh @ x_proj_w[0:80]^T (split-K 8 x Kc=256) -> fp16, + C_last
    skgemm2<<<dim3(8, ML / 128, 1), 256, 0, stream>>>(uh, DIn, xp_h, DIn, skp, XPW, 256);
    skcombB_clast<<<1296, 256, 0, stream>>>(skp, dtBh, uh, x_proj, Clast);
    // 5. deltah = fp16(softplus(dt @ dt_proj_w^T + dt_proj_b))  (region A: wfoldP dead)
    hgemm<1, true><<<dim3(DIn / 128, ML / 128), 256, 0, stream>>>(
        dtBh, XPW, dt_wh, DTRn, dt_b, deltah, DIn, DIn, DTRn);
    // 6. chunked scan, 64 chunks of 16 steps (region B: skp dead)
    scan_chunk_kernel<<<dim3(DIn / 256, NCHUNK, Bn), 256, 0, stream>>>(
        deltah, uh, dtBh, A_log, cS, cH);
    // 7. combine + gate + weff dot + atomic accumulate into out
    combine_v3<<<dim3(DIn / 16, Bn), 256, 0, stream>>>(
        cS, cH, A_log, Clast, Dp, uh, zlast, wp, out);
}